// Round 7
// baseline (125.288 us; speedup 1.0000x reference)
//
#include <hip/hip_runtime.h>
#include <math.h>

// ---------------------------------------------------------------------------
// PCA local frames, single-kernel, round 7: register solver + more waves.
//
// Bottleneck history:
//   r4: solver state in scratch (~200cyc/acc)                   46.8us
//   r5: solver state in LDS (~120cyc dependent ds_read)         ~41us
//   r6: solver state in VGPRs via select chains — instruction
//       stream grew (cndmask fans + exec-mask union over 16
//       divergent lanes) and at 2 stage-2 waves/SIMD the dep
//       chains can't hide: VALUBusy 37%, 50.7us.
//   r7: SAME solver (token-identical, bit-exact), geometry change:
//       32 nodes/block, stage 2 = 4 waves x 8 lanes  -> 4096
//       stage-2 wave-streams = 4/SIMD (grid 1024 = 4 blocks/CU,
//       LDS 24.7KB). Doubled wave interleave fills the dep-stall
//       gaps; divergence union shrinks 16->8 lanes.
//
// Round-3 lesson: no cross-kernel d_ws producer/consumer (graph-replay
// divergence).  Single kernel, LDS only for edge-vector staging.
//
// Sign-exactness (validated round 2): replicate numpy's CPU ssyevd path:
// SSYTD2(lower) -> SSTEQR('I') -> SLARF1F, OpenBLAS-FMA BLAS tails,
// contract-off everywhere else.  DO NOT change summation order or FMA
// placement — rank-deficient corner nodes are rounding-trajectory-determined.
// iscale paths are reachable (near-coincident neighbors -> anorm < ~3e-5):
// keep every guard.
// ---------------------------------------------------------------------------

#pragma clang fp contract(off)

#define EPS_F32    5.9604645e-8f     /* SLAMCH('E') = 2^-24            */
#define SAFMIN_F32 1.17549435e-38f   /* SLAMCH('S') = 2^-126           */

__device__ __forceinline__ float lapy2f(float x, float y) {
#pragma clang fp contract(off)
  float xa = fabsf(x), ya = fabsf(y);
  float w = fmaxf(xa, ya);
  float z = fminf(xa, ya);
  if (z == 0.0f) return w;
  float t = z / w;
  return w * sqrtf(1.0f + t * t);
}

// LAPACK >= 3.10 slartg (float32).
__device__ __forceinline__ void slartgf(float f, float g, float* c, float* s, float* r) {
#pragma clang fp contract(off)
  const float safmin = SAFMIN_F32;
  const float safmax = 8.50705917e37f;   // 1/safmin
  const float rtmin  = 1.08420217e-19f;  // sqrt(safmin)
  const float rtmax  = 6.52530446e18f;   // sqrt(safmax/2)
  if (g == 0.0f) { *c = 1.0f; *s = 0.0f; *r = f; return; }
  if (f == 0.0f) { *c = 0.0f; *s = copysignf(1.0f, g); *r = fabsf(g); return; }
  float f1 = fabsf(f), g1 = fabsf(g);
  if (f1 > rtmin && f1 < rtmax && g1 > rtmin && g1 < rtmax) {
    float d = sqrtf(f * f + g * g);
    *c = f1 / d;
    *r = copysignf(d, f);
    *s = g / (*r);
  } else {
    float u  = fminf(safmax, fmaxf(safmin, fmaxf(f1, g1)));
    float fs = f / u, gs = g / u;
    float d  = sqrtf(fs * fs + gs * gs);
    *c = fabsf(fs) / d;
    float rr = copysignf(d, f);
    *s = gs / rr;
    *r = rr * u;
  }
}

// LAPACK slaev2 (float32), verbatim transcription.
__device__ __forceinline__ void slaev2f(float a, float b, float c,
                                        float* rt1, float* rt2,
                                        float* cs1, float* sn1) {
#pragma clang fp contract(off)
  float sm  = a + c;
  float df  = a - c;
  float adf = fabsf(df);
  float tb  = b + b;
  float ab  = fabsf(tb);
  float acmx, acmn;
  if (fabsf(a) > fabsf(c)) { acmx = a; acmn = c; } else { acmx = c; acmn = a; }
  float rt;
  if (adf > ab)      { float t = ab / adf; rt = adf * sqrtf(1.0f + t * t); }
  else if (adf < ab) { float t = adf / ab; rt = ab  * sqrtf(1.0f + t * t); }
  else               { rt = ab * sqrtf(2.0f); }
  int sgn1;
  if (sm < 0.0f) {
    *rt1 = 0.5f * (sm - rt); sgn1 = -1;
    *rt2 = (acmx / *rt1) * acmn - (b / *rt1) * b;
  } else if (sm > 0.0f) {
    *rt1 = 0.5f * (sm + rt); sgn1 = 1;
    *rt2 = (acmx / *rt1) * acmn - (b / *rt1) * b;
  } else {
    *rt1 = 0.5f * rt; *rt2 = -0.5f * rt; sgn1 = 1;
  }
  int sgn2; float cs;
  if (df >= 0.0f) { cs = df + rt; sgn2 = 1; }
  else            { cs = df - rt; sgn2 = -1; }
  float acs = fabsf(cs);
  if (acs > ab) {
    float ct = -tb / cs;
    *sn1 = 1.0f / sqrtf(1.0f + ct * ct);
    *cs1 = ct * (*sn1);
  } else {
    if (ab == 0.0f) { *cs1 = 1.0f; *sn1 = 0.0f; }
    else {
      float tn = -cs / tb;
      *cs1 = 1.0f / sqrtf(1.0f + tn * tn);
      *sn1 = tn * (*cs1);
    }
  }
  if (sgn1 == sgn2) { float tn = *cs1; *cs1 = -(*sn1); *sn1 = tn; }
}

// ---------------------------------------------------------------------------
// cov -> frames, ALL state in scalar registers.  Dynamic indices resolved by
// select chains.  Token-identical to the validated round-6 version.
// ---------------------------------------------------------------------------
__device__ void eig_frames_reg(float c00, float c01, float c02,
                               float c11, float c12, float c22,
                               float* __restrict__ o) {
#pragma clang fp contract(off)
  // ---- SSYTD2, n=3, lower (one Householder), OpenBLAS-FMA BLAS model ----
  float d1, d2, d3, e1, e2, tau1, v2;
  {
    float a11 = c00, a21 = c01, a31 = c02, a22 = c11, a32 = c12, a33 = c22;
    float xnorm = fabsf(a31);
    if (xnorm == 0.0f) {
      tau1 = 0.0f; v2 = 0.0f;
      d1 = a11; d2 = a22; d3 = a33;
      e1 = a21; e2 = a32;
    } else {
      float py2  = lapy2f(a21, xnorm);
      float beta = -copysignf(py2, a21);
      tau1 = (beta - a21) / beta;
      v2   = a31 * (1.0f / (a21 - beta));
      float t2 = a32 * v2;
      float w1 = __builtin_fmaf(tau1, t2, tau1 * a22);
      float w2 = __builtin_fmaf(tau1 * v2, a33, tau1 * a32);
      float dot = __builtin_fmaf(v2, w2, w1);
      float ac = (-0.5f * tau1) * dot;
      w1 = w1 + ac;
      w2 = __builtin_fmaf(ac, v2, w2);
      float A11 = a22 - w1;
      A11 = A11 - w1;
      float A21 = a32 - w2;
      A21 = __builtin_fmaf(-w1, v2, A21);
      float A33 = __builtin_fmaf(-v2, w2, a33);
      A33 = __builtin_fmaf(-w2, v2, A33);
      d1 = a11; d2 = A11; d3 = A33;
      e1 = beta; e2 = A21;
    }
  }

  // ---- SSTEQR('I'), n=3, register-resident ----
  float z11 = 1.0f, z12 = 0.0f, z13 = 0.0f;
  float z21 = 0.0f, z22 = 1.0f, z23 = 0.0f;
  float z31 = 0.0f, z32 = 0.0f, z33 = 1.0f;
  float wc0 = 0.0f, wc1 = 0.0f, ws0 = 0.0f, ws1 = 0.0f;

#define DGET(i)    ((i) == 1 ? d1 : (i) == 2 ? d2 : d3)
#define DSET(i,v)  do { float _t = (v); if ((i) == 1) d1 = _t; else if ((i) == 2) d2 = _t; else d3 = _t; } while (0)
#define EGET(i)    ((i) == 1 ? e1 : e2)
#define ESET(i,v)  do { float _t = (v); if ((i) == 1) e1 = _t; else e2 = _t; } while (0)
#define WCGET(q)   ((q) == 0 ? wc0 : wc1)
#define WCSET(q,v) do { float _t = (v); if ((q) == 0) wc0 = _t; else wc1 = _t; } while (0)
#define WSGET(q)   ((q) == 0 ? ws0 : ws1)
#define WSSET(q,v) do { float _t = (v); if ((q) == 0) ws0 = _t; else ws1 = _t; } while (0)
#define ZGET(r,c)  ((r) == 1 ? ((c) == 1 ? z11 : (c) == 2 ? z12 : z13) \
                  : (r) == 2 ? ((c) == 1 ? z21 : (c) == 2 ? z22 : z23) \
                  :            ((c) == 1 ? z31 : (c) == 2 ? z32 : z33))
#define ZSET(r,c,v) do { float _t = (v); \
    if ((r) == 1)      { if ((c) == 1) z11 = _t; else if ((c) == 2) z12 = _t; else z13 = _t; } \
    else if ((r) == 2) { if ((c) == 1) z21 = _t; else if ((c) == 2) z22 = _t; else z23 = _t; } \
    else               { if ((c) == 1) z31 = _t; else if ((c) == 2) z32 = _t; else z33 = _t; } } while (0)

  {
    const float eps    = EPS_F32;
    const float eps2   = eps * eps;
    const float safmin = SAFMIN_F32;
    const float ssfmax = sqrtf(8.50705917e37f) / 3.0f;
    const float ssfmin = sqrtf(safmin) / eps2;

    int   l1, l, m, lsv, lend, lendsv, iscale;
    const int nmaxit = 90;
    int   jtot = 0;
    float anorm, p, g, r, rt1, rt2, rc, rs, f, b;

    l1 = 1;

L10:
    if (l1 > 3) goto L160;
    if (l1 > 1) ESET(l1 - 1, 0.0f);
    if (l1 <= 2) {
      for (m = l1; m <= 2; m++) {
        float tst = fabsf(EGET(m));
        if (tst == 0.0f) goto L30;
        if (tst <= (sqrtf(fabsf(DGET(m))) * sqrtf(fabsf(DGET(m + 1)))) * eps) {
          ESET(m, 0.0f);
          goto L30;
        }
      }
    }
    m = 3;
L30:
    l = l1; lsv = l; lend = m; lendsv = lend; l1 = m + 1;
    if (lend == l) goto L10;

    // anorm = slanst('M', ...)
    anorm = 0.0f;
    for (int q = l; q <= lend; q++)     anorm = fmaxf(anorm, fabsf(DGET(q)));
    for (int q = l; q <= lend - 1; q++) anorm = fmaxf(anorm, fabsf(EGET(q)));
    iscale = 0;
    if (anorm == 0.0f) goto L10;
    if (anorm > ssfmax) {
      iscale = 1;
      float sc = ssfmax / anorm;
      for (int q = l; q <= lend; q++)     DSET(q, DGET(q) * sc);
      for (int q = l; q <= lend - 1; q++) ESET(q, EGET(q) * sc);
    } else if (anorm < ssfmin) {
      iscale = 2;
      float sc = ssfmin / anorm;
      for (int q = l; q <= lend; q++)     DSET(q, DGET(q) * sc);
      for (int q = l; q <= lend - 1; q++) ESET(q, EGET(q) * sc);
    }

    if (fabsf(DGET(lend)) < fabsf(DGET(l))) { lend = lsv; l = lendsv; }

    if (lend > l) {
      // ---------------- QL iteration ----------------
L40:
      if (l != lend) {
        for (m = l; m <= lend - 1; m++) {
          float tst = EGET(m) * EGET(m);
          if (tst <= (eps2 * fabsf(DGET(m))) * fabsf(DGET(m + 1)) + safmin) goto L60;
        }
      }
      m = lend;
L60:
      if (m < lend) ESET(m, 0.0f);
      p = DGET(l);
      if (m == l) goto L80;
      if (m == l + 1) {
        slaev2f(DGET(l), EGET(l), DGET(l + 1), &rt1, &rt2, &rc, &rs);
        WCSET(l - 1, rc);
        WSSET(l - 1, rs);
        // slasr 'R','V','B', 1 rotation on cols (l, l+1)
        #pragma unroll
        for (int row = 1; row <= 3; row++) {
          float t  = ZGET(row, l + 1);
          float zl = ZGET(row, l);
          ZSET(row, l + 1, rc * t - rs * zl);
          ZSET(row, l,     rs * t + rc * zl);
        }
        DSET(l, rt1); DSET(l + 1, rt2); ESET(l, 0.0f);
        l += 2;
        if (l <= lend) goto L40;
        goto L140;
      }
      if (jtot == nmaxit) goto L140;
      jtot++;
      g = (DGET(l + 1) - p) / (2.0f * EGET(l));
      r = lapy2f(g, 1.0f);
      g = DGET(m) - p + (EGET(l) / (g + copysignf(r, g)));
      rs = 1.0f; rc = 1.0f; p = 0.0f;
      for (int i = m - 1; i >= l; i--) {
        f = rs * EGET(i);
        b = rc * EGET(i);
        slartgf(g, f, &rc, &rs, &r);
        if (i != m - 1) ESET(i + 1, r);
        g = DGET(i + 1) - p;
        r = (DGET(i) - g) * rs + 2.0f * rc * b;
        p = rs * r;
        DSET(i + 1, g + p);
        g = rc * r - b;
        WCSET(i - 1, rc);
        WSSET(i - 1, -rs);
      }
      {
        int mm = m - l + 1;  // slasr 'R','V','B'
        for (int j = mm - 1; j >= 1; j--) {
          float cj = WCGET(l + j - 2);
          float sj = WSGET(l + j - 2);
          if (cj != 1.0f || sj != 0.0f) {
            int col = l + j - 1;
            #pragma unroll
            for (int row = 1; row <= 3; row++) {
              float t  = ZGET(row, col + 1);
              float zc = ZGET(row, col);
              ZSET(row, col + 1, cj * t - sj * zc);
              ZSET(row, col,     sj * t + cj * zc);
            }
          }
        }
      }
      DSET(l, DGET(l) - p);
      ESET(l, g);
      goto L40;
L80:
      DSET(l, p);
      l++;
      if (l <= lend) goto L40;
      goto L140;
    } else {
      // ---------------- QR iteration ----------------
L90:
      if (l != lend) {
        for (m = l; m >= lend + 1; m--) {
          float tst = EGET(m - 1) * EGET(m - 1);
          if (tst <= (eps2 * fabsf(DGET(m))) * fabsf(DGET(m - 1)) + safmin) goto L110;
        }
      }
      m = lend;
L110:
      if (m > lend) ESET(m - 1, 0.0f);
      p = DGET(l);
      if (m == l) goto L130;
      if (m == l - 1) {
        slaev2f(DGET(l - 1), EGET(l - 1), DGET(l), &rt1, &rt2, &rc, &rs);
        WCSET(m - 1, rc);
        WSSET(m - 1, rs);
        // slasr 'R','V','F', 1 rotation on cols (l-1, l)
        #pragma unroll
        for (int row = 1; row <= 3; row++) {
          float t  = ZGET(row, l);
          float zl = ZGET(row, l - 1);
          ZSET(row, l,     rc * t - rs * zl);
          ZSET(row, l - 1, rs * t + rc * zl);
        }
        DSET(l - 1, rt1); DSET(l, rt2); ESET(l - 1, 0.0f);
        l -= 2;
        if (l >= lend) goto L90;
        goto L140;
      }
      if (jtot == nmaxit) goto L140;
      jtot++;
      g = (DGET(l - 1) - p) / (2.0f * EGET(l - 1));
      r = lapy2f(g, 1.0f);
      g = DGET(m) - p + (EGET(l - 1) / (g + copysignf(r, g)));
      rs = 1.0f; rc = 1.0f; p = 0.0f;
      for (int i = m; i <= l - 1; i++) {
        f = rs * EGET(i);
        b = rc * EGET(i);
        slartgf(g, f, &rc, &rs, &r);
        if (i != m) ESET(i - 1, r);
        g = DGET(i) - p;
        r = (DGET(i + 1) - g) * rs + 2.0f * rc * b;
        p = rs * r;
        DSET(i, g + p);
        g = rc * r - b;
        WCSET(i - 1, rc);
        WSSET(i - 1, rs);
      }
      {
        int mm = l - m + 1;  // slasr 'R','V','F'
        for (int j = 1; j <= mm - 1; j++) {
          float cj = WCGET(m + j - 2);
          float sj = WSGET(m + j - 2);
          if (cj != 1.0f || sj != 0.0f) {
            int col = m + j - 1;
            #pragma unroll
            for (int row = 1; row <= 3; row++) {
              float t  = ZGET(row, col + 1);
              float zc = ZGET(row, col);
              ZSET(row, col + 1, cj * t - sj * zc);
              ZSET(row, col,     sj * t + cj * zc);
            }
          }
        }
      }
      DSET(l, DGET(l) - p);
      ESET(l - 1, g);
      goto L90;
L130:
      DSET(l, p);
      l--;
      if (l >= lend) goto L90;
      goto L140;
    }

L140:
    if (iscale == 1) {
      float sc = anorm / ssfmax;
      for (int q = lsv; q <= lendsv; q++)     DSET(q, DGET(q) * sc);
      for (int q = lsv; q <= lendsv - 1; q++) ESET(q, EGET(q) * sc);
    } else if (iscale == 2) {
      float sc = anorm / ssfmin;
      for (int q = lsv; q <= lendsv; q++)     DSET(q, DGET(q) * sc);
      for (int q = lsv; q <= lendsv - 1; q++) ESET(q, EGET(q) * sc);
    }
    if (jtot < nmaxit) goto L10;
    goto L160;

L160:
    // ascending selection sort with column swaps (ssteqr tail, icompz>0)
    for (int ii = 2; ii <= 3; ii++) {
      int i = ii - 1, kk = i;
      p = DGET(i);
      for (int j = ii; j <= 3; j++) {
        if (DGET(j) < p) { kk = j; p = DGET(j); }
      }
      if (kk != i) {
        DSET(kk, DGET(i));
        DSET(i, p);
        #pragma unroll
        for (int row = 1; row <= 3; row++) {
          float t = ZGET(row, i);
          ZSET(row, i, ZGET(row, kk));
          ZSET(row, kk, t);
        }
      }
    }
  }

#undef DGET
#undef DSET
#undef EGET
#undef ESET
#undef WCGET
#undef WCSET
#undef WSGET
#undef WSSET
#undef ZGET
#undef ZSET

  // ---- SORM2R / SLARF1F: rows 2..3 of Z, u = (0, 1, v2) ----
  if (tau1 != 0.0f) {
    {
      float z2 = z21, z3 = z31;
      float w = z2 + z3 * v2;
      float t = tau1 * w;
      z21 = __builtin_fmaf(-tau1, w, z2);
      z31 = __builtin_fmaf(v2, -t, z3);
    }
    {
      float z2 = z22, z3 = z32;
      float w = z2 + z3 * v2;
      float t = tau1 * w;
      z22 = __builtin_fmaf(-tau1, w, z2);
      z32 = __builtin_fmaf(v2, -t, z3);
    }
    {
      float z2 = z23, z3 = z33;
      float w = z2 + z3 * v2;
      float t = tau1 * w;
      z23 = __builtin_fmaf(-tau1, w, z2);
      z33 = __builtin_fmaf(v2, -t, z3);
    }
  }

  // frames = vecs^T
  o[0] = z11; o[1] = z21; o[2] = z31;
  o[3] = z12; o[4] = z22; o[5] = z32;
  o[6] = z13; o[7] = z23; o[8] = z33;
}

// ---------------------------------------------------------------------------
// Tiled single kernel: 256 threads / 32 nodes per block.
//   sev[node*193 + slot*3 + c] : conflict-free both phases.
//   Stage 1: 8 gather iterations (2048 edges / 256 threads).
//   Stage 2: 4 waves x 8 lanes (wave w -> nodes 8w..8w+7), register solver.
//   Grid n/32 = 1024 blocks = 4 blocks/CU (LDS 24.7KB, fits 6) ->
//   4 stage-2 waves/SIMD for dep-chain hiding.
// ---------------------------------------------------------------------------
#define NODES_PER_BLOCK 32
#define NODE_STRIDE     193   /* 64*3 + 1 pad */
#define SOLVER_LANES    8

struct __attribute__((aligned(4))) f3 { float x, y, z; };

__global__ void __launch_bounds__(256)
pca_frames_tiled_kernel(const float* __restrict__ pos,
                        const int*   __restrict__ esrc,
                        const int*   __restrict__ nn,
                        float*       __restrict__ out,
                        int n)
{
#pragma clang fp contract(off)
  __shared__ float sev[NODES_PER_BLOCK * NODE_STRIDE];          // 24704 B

  const int tid   = threadIdx.x;
  const int node0 = blockIdx.x * NODES_PER_BLOCK;

  // ---- Stage 1: cooperative gather of this block's 32*64 edges ----
  const int ebase = blockIdx.x * (NODES_PER_BLOCK * 64);
  #pragma unroll
  for (int q = 0; q < (NODES_PER_BLOCK * 64) / 256; ++q) {
    int eb  = q * 256 + tid;
    int n_b = eb >> 6;          // wave-uniform
    int j   = eb & 63;
    int i   = node0 + n_b;
    int s   = esrc[ebase + eb];
    f3 ps   = *reinterpret_cast<const f3*>(pos + 3 * s);   // packed 12B gather
    // dst pos reads are wave-uniform (broadcast); rounding identical: rn(a-b)
    float dx = ps.x - pos[3 * i + 0];
    float dy = ps.y - pos[3 * i + 1];
    float dz = ps.z - pos[3 * i + 2];
    float* row = sev + n_b * NODE_STRIDE + 3 * j;
    row[0] = dx;
    row[1] = dy;
    row[2] = dz;
  }

  __syncthreads();

  // ---- Stage 2: 4 waves x 8 lanes, one node per lane ----
  const int w = tid >> 6;
  const int l = tid & 63;
  if (l < SOLVER_LANES) {
    int nb = w * SOLVER_LANES + l;   // block-local node 0..31
    int i  = node0 + nb;
    float* o = out + (size_t)i * 9;

    if (nn[i] <= 1) {
      #pragma unroll
      for (int j = 0; j < 9; ++j) o[j] = 0.0f;
      return;
    }

    const float* row = sev + nb * NODE_STRIDE;
    float c00 = 0.0f, c01 = 0.0f, c02 = 0.0f, c11 = 0.0f, c12 = 0.0f, c22 = 0.0f;
    // EXACT sequential edge order, EXACT rounding (validated).
    for (int j = 0; j < 64; ++j) {
      float dx = row[3 * j + 0];
      float dy = row[3 * j + 1];
      float dz = row[3 * j + 2];
      c00 = c00 + dx * dx;
      c01 = c01 + dx * dy;
      c02 = c02 + dx * dz;
      c11 = c11 + dy * dy;
      c12 = c12 + dy * dz;
      c22 = c22 + dz * dz;
    }

    eig_frames_reg(c00, c01, c02, c11, c12, c22, o);
  }
}

// ---------------------------------------------------------------------------
// Fallback (unexpected shapes): validated fused structure, register solver.
// ---------------------------------------------------------------------------
__global__ void __launch_bounds__(64)
pca_frames_fused_kernel(const float* __restrict__ pos,
                        const int*   __restrict__ esrc,
                        const int*   __restrict__ nn,
                        float*       __restrict__ out,
                        int n, int k)
{
#pragma clang fp contract(off)
  int i = blockIdx.x * blockDim.x + threadIdx.x;
  if (i >= n) return;
  float* o = out + (size_t)i * 9;

  if (nn[i] <= 1) {
    #pragma unroll
    for (int j = 0; j < 9; ++j) o[j] = 0.0f;
    return;
  }

  float px = pos[3 * i + 0], py = pos[3 * i + 1], pz = pos[3 * i + 2];
  float c00 = 0.0f, c01 = 0.0f, c02 = 0.0f, c11 = 0.0f, c12 = 0.0f, c22 = 0.0f;
  const int* ep = esrc + (size_t)i * k;
  for (int j = 0; j < k; ++j) {
    int sidx = ep[j];
    float dx = pos[3 * sidx + 0] - px;
    float dy = pos[3 * sidx + 1] - py;
    float dz = pos[3 * sidx + 2] - pz;
    c00 = c00 + dx * dx;
    c01 = c01 + dx * dy;
    c02 = c02 + dx * dz;
    c11 = c11 + dy * dy;
    c12 = c12 + dy * dz;
    c22 = c22 + dz * dz;
  }

  eig_frames_reg(c00, c01, c02, c11, c12, c22, o);
}

extern "C" void kernel_launch(void* const* d_in, const int* in_sizes, int n_in,
                              void* d_out, int out_size, void* d_ws, size_t ws_size,
                              hipStream_t stream) {
  const float* pos  = (const float*)d_in[0];
  const int*   esrc = (const int*)d_in[1];
  // d_in[2] = edge_dst: unused (layout is repeat(arange(n), k) by construction)
  const int*   nn   = (const int*)d_in[3];
  float*       out  = (float*)d_out;

  int n = in_sizes[0] / 3;
  if (n <= 0) return;
  int k = in_sizes[1] / n;

  if (k == 64 && (n % NODES_PER_BLOCK) == 0) {
    hipLaunchKernelGGL(pca_frames_tiled_kernel, dim3(n / NODES_PER_BLOCK),
                       dim3(256), 0, stream, pos, esrc, nn, out, n);
  } else {
    const int block = 64;
    hipLaunchKernelGGL(pca_frames_fused_kernel, dim3((n + block - 1) / block),
                       dim3(block), 0, stream, pos, esrc, nn, out, n, k);
  }
}

// Round 8
// 109.775 us; speedup vs baseline: 1.1413x; 1.1413x over previous
//
#include <hip/hip_runtime.h>
#include <math.h>

// ---------------------------------------------------------------------------
// PCA local frames, single-kernel, round 8: register solver, 64-lane stage 2.
//
// Issue-accounting lesson (r6/r7): with L active solver lanes per wave the
// GPU issues (N/L) x S_union instructions, and S_union (exec-mask union of
// divergent solver trajectories) is nearly independent of L.  r7 (L=8)
// doubled total issue vs r6 (L=16): 56%x63.5us vs 37%x50.7us.  So maximize
// L: stage 2 = ONE 64-lane wave per 64-node block (512 waves total, minimum
// possible issue volume).  Register solver (r6) + r4 geometry — the one
// combination not yet measured.  Interleave comes from co-resident blocks'
// stage-1 waves (2 blocks/CU at 49.4KB LDS).
//
// Round-3 lesson: no cross-kernel d_ws producer/consumer (graph-replay
// divergence).  Single kernel, LDS only for edge-vector staging.
//
// Sign-exactness (validated round 2): replicate numpy's CPU ssyevd path:
// SSYTD2(lower) -> SSTEQR('I') -> SLARF1F, OpenBLAS-FMA BLAS tails,
// contract-off everywhere else.  DO NOT change summation order or FMA
// placement — rank-deficient corner nodes are rounding-trajectory-determined.
// ---------------------------------------------------------------------------

#pragma clang fp contract(off)

#define EPS_F32    5.9604645e-8f     /* SLAMCH('E') = 2^-24            */
#define SAFMIN_F32 1.17549435e-38f   /* SLAMCH('S') = 2^-126           */

__device__ __forceinline__ float lapy2f(float x, float y) {
#pragma clang fp contract(off)
  float xa = fabsf(x), ya = fabsf(y);
  float w = fmaxf(xa, ya);
  float z = fminf(xa, ya);
  if (z == 0.0f) return w;
  float t = z / w;
  return w * sqrtf(1.0f + t * t);
}

// LAPACK >= 3.10 slartg (float32).
__device__ __forceinline__ void slartgf(float f, float g, float* c, float* s, float* r) {
#pragma clang fp contract(off)
  const float safmin = SAFMIN_F32;
  const float safmax = 8.50705917e37f;   // 1/safmin
  const float rtmin  = 1.08420217e-19f;  // sqrt(safmin)
  const float rtmax  = 6.52530446e18f;   // sqrt(safmax/2)
  if (g == 0.0f) { *c = 1.0f; *s = 0.0f; *r = f; return; }
  if (f == 0.0f) { *c = 0.0f; *s = copysignf(1.0f, g); *r = fabsf(g); return; }
  float f1 = fabsf(f), g1 = fabsf(g);
  if (f1 > rtmin && f1 < rtmax && g1 > rtmin && g1 < rtmax) {
    float d = sqrtf(f * f + g * g);
    *c = f1 / d;
    *r = copysignf(d, f);
    *s = g / (*r);
  } else {
    float u  = fminf(safmax, fmaxf(safmin, fmaxf(f1, g1)));
    float fs = f / u, gs = g / u;
    float d  = sqrtf(fs * fs + gs * gs);
    *c = fabsf(fs) / d;
    float rr = copysignf(d, f);
    *s = gs / rr;
    *r = rr * u;
  }
}

// LAPACK slaev2 (float32), verbatim transcription.
__device__ __forceinline__ void slaev2f(float a, float b, float c,
                                        float* rt1, float* rt2,
                                        float* cs1, float* sn1) {
#pragma clang fp contract(off)
  float sm  = a + c;
  float df  = a - c;
  float adf = fabsf(df);
  float tb  = b + b;
  float ab  = fabsf(tb);
  float acmx, acmn;
  if (fabsf(a) > fabsf(c)) { acmx = a; acmn = c; } else { acmx = c; acmn = a; }
  float rt;
  if (adf > ab)      { float t = ab / adf; rt = adf * sqrtf(1.0f + t * t); }
  else if (adf < ab) { float t = adf / ab; rt = ab  * sqrtf(1.0f + t * t); }
  else               { rt = ab * sqrtf(2.0f); }
  int sgn1;
  if (sm < 0.0f) {
    *rt1 = 0.5f * (sm - rt); sgn1 = -1;
    *rt2 = (acmx / *rt1) * acmn - (b / *rt1) * b;
  } else if (sm > 0.0f) {
    *rt1 = 0.5f * (sm + rt); sgn1 = 1;
    *rt2 = (acmx / *rt1) * acmn - (b / *rt1) * b;
  } else {
    *rt1 = 0.5f * rt; *rt2 = -0.5f * rt; sgn1 = 1;
  }
  int sgn2; float cs;
  if (df >= 0.0f) { cs = df + rt; sgn2 = 1; }
  else            { cs = df - rt; sgn2 = -1; }
  float acs = fabsf(cs);
  if (acs > ab) {
    float ct = -tb / cs;
    *sn1 = 1.0f / sqrtf(1.0f + ct * ct);
    *cs1 = ct * (*sn1);
  } else {
    if (ab == 0.0f) { *cs1 = 1.0f; *sn1 = 0.0f; }
    else {
      float tn = -cs / tb;
      *cs1 = 1.0f / sqrtf(1.0f + tn * tn);
      *sn1 = tn * (*cs1);
    }
  }
  if (sgn1 == sgn2) { float tn = *cs1; *cs1 = -(*sn1); *sn1 = tn; }
}

// ---------------------------------------------------------------------------
// cov -> frames, ALL state in scalar registers.  Dynamic indices resolved by
// select chains.  Token-identical to the validated round-6 version.
// ---------------------------------------------------------------------------
__device__ void eig_frames_reg(float c00, float c01, float c02,
                               float c11, float c12, float c22,
                               float* __restrict__ o) {
#pragma clang fp contract(off)
  // ---- SSYTD2, n=3, lower (one Householder), OpenBLAS-FMA BLAS model ----
  float d1, d2, d3, e1, e2, tau1, v2;
  {
    float a11 = c00, a21 = c01, a31 = c02, a22 = c11, a32 = c12, a33 = c22;
    float xnorm = fabsf(a31);
    if (xnorm == 0.0f) {
      tau1 = 0.0f; v2 = 0.0f;
      d1 = a11; d2 = a22; d3 = a33;
      e1 = a21; e2 = a32;
    } else {
      float py2  = lapy2f(a21, xnorm);
      float beta = -copysignf(py2, a21);
      tau1 = (beta - a21) / beta;
      v2   = a31 * (1.0f / (a21 - beta));
      float t2 = a32 * v2;
      float w1 = __builtin_fmaf(tau1, t2, tau1 * a22);
      float w2 = __builtin_fmaf(tau1 * v2, a33, tau1 * a32);
      float dot = __builtin_fmaf(v2, w2, w1);
      float ac = (-0.5f * tau1) * dot;
      w1 = w1 + ac;
      w2 = __builtin_fmaf(ac, v2, w2);
      float A11 = a22 - w1;
      A11 = A11 - w1;
      float A21 = a32 - w2;
      A21 = __builtin_fmaf(-w1, v2, A21);
      float A33 = __builtin_fmaf(-v2, w2, a33);
      A33 = __builtin_fmaf(-w2, v2, A33);
      d1 = a11; d2 = A11; d3 = A33;
      e1 = beta; e2 = A21;
    }
  }

  // ---- SSTEQR('I'), n=3, register-resident ----
  float z11 = 1.0f, z12 = 0.0f, z13 = 0.0f;
  float z21 = 0.0f, z22 = 1.0f, z23 = 0.0f;
  float z31 = 0.0f, z32 = 0.0f, z33 = 1.0f;
  float wc0 = 0.0f, wc1 = 0.0f, ws0 = 0.0f, ws1 = 0.0f;

#define DGET(i)    ((i) == 1 ? d1 : (i) == 2 ? d2 : d3)
#define DSET(i,v)  do { float _t = (v); if ((i) == 1) d1 = _t; else if ((i) == 2) d2 = _t; else d3 = _t; } while (0)
#define EGET(i)    ((i) == 1 ? e1 : e2)
#define ESET(i,v)  do { float _t = (v); if ((i) == 1) e1 = _t; else e2 = _t; } while (0)
#define WCGET(q)   ((q) == 0 ? wc0 : wc1)
#define WCSET(q,v) do { float _t = (v); if ((q) == 0) wc0 = _t; else wc1 = _t; } while (0)
#define WSGET(q)   ((q) == 0 ? ws0 : ws1)
#define WSSET(q,v) do { float _t = (v); if ((q) == 0) ws0 = _t; else ws1 = _t; } while (0)
#define ZGET(r,c)  ((r) == 1 ? ((c) == 1 ? z11 : (c) == 2 ? z12 : z13) \
                  : (r) == 2 ? ((c) == 1 ? z21 : (c) == 2 ? z22 : z23) \
                  :            ((c) == 1 ? z31 : (c) == 2 ? z32 : z33))
#define ZSET(r,c,v) do { float _t = (v); \
    if ((r) == 1)      { if ((c) == 1) z11 = _t; else if ((c) == 2) z12 = _t; else z13 = _t; } \
    else if ((r) == 2) { if ((c) == 1) z21 = _t; else if ((c) == 2) z22 = _t; else z23 = _t; } \
    else               { if ((c) == 1) z31 = _t; else if ((c) == 2) z32 = _t; else z33 = _t; } } while (0)

  {
    const float eps    = EPS_F32;
    const float eps2   = eps * eps;
    const float safmin = SAFMIN_F32;
    const float ssfmax = sqrtf(8.50705917e37f) / 3.0f;
    const float ssfmin = sqrtf(safmin) / eps2;

    int   l1, l, m, lsv, lend, lendsv, iscale;
    const int nmaxit = 90;
    int   jtot = 0;
    float anorm, p, g, r, rt1, rt2, rc, rs, f, b;

    l1 = 1;

L10:
    if (l1 > 3) goto L160;
    if (l1 > 1) ESET(l1 - 1, 0.0f);
    if (l1 <= 2) {
      for (m = l1; m <= 2; m++) {
        float tst = fabsf(EGET(m));
        if (tst == 0.0f) goto L30;
        if (tst <= (sqrtf(fabsf(DGET(m))) * sqrtf(fabsf(DGET(m + 1)))) * eps) {
          ESET(m, 0.0f);
          goto L30;
        }
      }
    }
    m = 3;
L30:
    l = l1; lsv = l; lend = m; lendsv = lend; l1 = m + 1;
    if (lend == l) goto L10;

    // anorm = slanst('M', ...)
    anorm = 0.0f;
    for (int q = l; q <= lend; q++)     anorm = fmaxf(anorm, fabsf(DGET(q)));
    for (int q = l; q <= lend - 1; q++) anorm = fmaxf(anorm, fabsf(EGET(q)));
    iscale = 0;
    if (anorm == 0.0f) goto L10;
    if (anorm > ssfmax) {
      iscale = 1;
      float sc = ssfmax / anorm;
      for (int q = l; q <= lend; q++)     DSET(q, DGET(q) * sc);
      for (int q = l; q <= lend - 1; q++) ESET(q, EGET(q) * sc);
    } else if (anorm < ssfmin) {
      iscale = 2;
      float sc = ssfmin / anorm;
      for (int q = l; q <= lend; q++)     DSET(q, DGET(q) * sc);
      for (int q = l; q <= lend - 1; q++) ESET(q, EGET(q) * sc);
    }

    if (fabsf(DGET(lend)) < fabsf(DGET(l))) { lend = lsv; l = lendsv; }

    if (lend > l) {
      // ---------------- QL iteration ----------------
L40:
      if (l != lend) {
        for (m = l; m <= lend - 1; m++) {
          float tst = EGET(m) * EGET(m);
          if (tst <= (eps2 * fabsf(DGET(m))) * fabsf(DGET(m + 1)) + safmin) goto L60;
        }
      }
      m = lend;
L60:
      if (m < lend) ESET(m, 0.0f);
      p = DGET(l);
      if (m == l) goto L80;
      if (m == l + 1) {
        slaev2f(DGET(l), EGET(l), DGET(l + 1), &rt1, &rt2, &rc, &rs);
        WCSET(l - 1, rc);
        WSSET(l - 1, rs);
        // slasr 'R','V','B', 1 rotation on cols (l, l+1)
        #pragma unroll
        for (int row = 1; row <= 3; row++) {
          float t  = ZGET(row, l + 1);
          float zl = ZGET(row, l);
          ZSET(row, l + 1, rc * t - rs * zl);
          ZSET(row, l,     rs * t + rc * zl);
        }
        DSET(l, rt1); DSET(l + 1, rt2); ESET(l, 0.0f);
        l += 2;
        if (l <= lend) goto L40;
        goto L140;
      }
      if (jtot == nmaxit) goto L140;
      jtot++;
      g = (DGET(l + 1) - p) / (2.0f * EGET(l));
      r = lapy2f(g, 1.0f);
      g = DGET(m) - p + (EGET(l) / (g + copysignf(r, g)));
      rs = 1.0f; rc = 1.0f; p = 0.0f;
      for (int i = m - 1; i >= l; i--) {
        f = rs * EGET(i);
        b = rc * EGET(i);
        slartgf(g, f, &rc, &rs, &r);
        if (i != m - 1) ESET(i + 1, r);
        g = DGET(i + 1) - p;
        r = (DGET(i) - g) * rs + 2.0f * rc * b;
        p = rs * r;
        DSET(i + 1, g + p);
        g = rc * r - b;
        WCSET(i - 1, rc);
        WSSET(i - 1, -rs);
      }
      {
        int mm = m - l + 1;  // slasr 'R','V','B'
        for (int j = mm - 1; j >= 1; j--) {
          float cj = WCGET(l + j - 2);
          float sj = WSGET(l + j - 2);
          if (cj != 1.0f || sj != 0.0f) {
            int col = l + j - 1;
            #pragma unroll
            for (int row = 1; row <= 3; row++) {
              float t  = ZGET(row, col + 1);
              float zc = ZGET(row, col);
              ZSET(row, col + 1, cj * t - sj * zc);
              ZSET(row, col,     sj * t + cj * zc);
            }
          }
        }
      }
      DSET(l, DGET(l) - p);
      ESET(l, g);
      goto L40;
L80:
      DSET(l, p);
      l++;
      if (l <= lend) goto L40;
      goto L140;
    } else {
      // ---------------- QR iteration ----------------
L90:
      if (l != lend) {
        for (m = l; m >= lend + 1; m--) {
          float tst = EGET(m - 1) * EGET(m - 1);
          if (tst <= (eps2 * fabsf(DGET(m))) * fabsf(DGET(m - 1)) + safmin) goto L110;
        }
      }
      m = lend;
L110:
      if (m > lend) ESET(m - 1, 0.0f);
      p = DGET(l);
      if (m == l) goto L130;
      if (m == l - 1) {
        slaev2f(DGET(l - 1), EGET(l - 1), DGET(l), &rt1, &rt2, &rc, &rs);
        WCSET(m - 1, rc);
        WSSET(m - 1, rs);
        // slasr 'R','V','F', 1 rotation on cols (l-1, l)
        #pragma unroll
        for (int row = 1; row <= 3; row++) {
          float t  = ZGET(row, l);
          float zl = ZGET(row, l - 1);
          ZSET(row, l,     rc * t - rs * zl);
          ZSET(row, l - 1, rs * t + rc * zl);
        }
        DSET(l - 1, rt1); DSET(l, rt2); ESET(l - 1, 0.0f);
        l -= 2;
        if (l >= lend) goto L90;
        goto L140;
      }
      if (jtot == nmaxit) goto L140;
      jtot++;
      g = (DGET(l - 1) - p) / (2.0f * EGET(l - 1));
      r = lapy2f(g, 1.0f);
      g = DGET(m) - p + (EGET(l - 1) / (g + copysignf(r, g)));
      rs = 1.0f; rc = 1.0f; p = 0.0f;
      for (int i = m; i <= l - 1; i++) {
        f = rs * EGET(i);
        b = rc * EGET(i);
        slartgf(g, f, &rc, &rs, &r);
        if (i != m) ESET(i - 1, r);
        g = DGET(i) - p;
        r = (DGET(i + 1) - g) * rs + 2.0f * rc * b;
        p = rs * r;
        DSET(i, g + p);
        g = rc * r - b;
        WCSET(i - 1, rc);
        WSSET(i - 1, rs);
      }
      {
        int mm = l - m + 1;  // slasr 'R','V','F'
        for (int j = 1; j <= mm - 1; j++) {
          float cj = WCGET(m + j - 2);
          float sj = WSGET(m + j - 2);
          if (cj != 1.0f || sj != 0.0f) {
            int col = m + j - 1;
            #pragma unroll
            for (int row = 1; row <= 3; row++) {
              float t  = ZGET(row, col + 1);
              float zc = ZGET(row, col);
              ZSET(row, col + 1, cj * t - sj * zc);
              ZSET(row, col,     sj * t + cj * zc);
            }
          }
        }
      }
      DSET(l, DGET(l) - p);
      ESET(l - 1, g);
      goto L90;
L130:
      DSET(l, p);
      l--;
      if (l >= lend) goto L90;
      goto L140;
    }

L140:
    if (iscale == 1) {
      float sc = anorm / ssfmax;
      for (int q = lsv; q <= lendsv; q++)     DSET(q, DGET(q) * sc);
      for (int q = lsv; q <= lendsv - 1; q++) ESET(q, EGET(q) * sc);
    } else if (iscale == 2) {
      float sc = anorm / ssfmin;
      for (int q = lsv; q <= lendsv; q++)     DSET(q, DGET(q) * sc);
      for (int q = lsv; q <= lendsv - 1; q++) ESET(q, EGET(q) * sc);
    }
    if (jtot < nmaxit) goto L10;
    goto L160;

L160:
    // ascending selection sort with column swaps (ssteqr tail, icompz>0)
    for (int ii = 2; ii <= 3; ii++) {
      int i = ii - 1, kk = i;
      p = DGET(i);
      for (int j = ii; j <= 3; j++) {
        if (DGET(j) < p) { kk = j; p = DGET(j); }
      }
      if (kk != i) {
        DSET(kk, DGET(i));
        DSET(i, p);
        #pragma unroll
        for (int row = 1; row <= 3; row++) {
          float t = ZGET(row, i);
          ZSET(row, i, ZGET(row, kk));
          ZSET(row, kk, t);
        }
      }
    }
  }

#undef DGET
#undef DSET
#undef EGET
#undef ESET
#undef WCGET
#undef WCSET
#undef WSGET
#undef WSSET
#undef ZGET
#undef ZSET

  // ---- SORM2R / SLARF1F: rows 2..3 of Z, u = (0, 1, v2) ----
  if (tau1 != 0.0f) {
    {
      float z2 = z21, z3 = z31;
      float w = z2 + z3 * v2;
      float t = tau1 * w;
      z21 = __builtin_fmaf(-tau1, w, z2);
      z31 = __builtin_fmaf(v2, -t, z3);
    }
    {
      float z2 = z22, z3 = z32;
      float w = z2 + z3 * v2;
      float t = tau1 * w;
      z22 = __builtin_fmaf(-tau1, w, z2);
      z32 = __builtin_fmaf(v2, -t, z3);
    }
    {
      float z2 = z23, z3 = z33;
      float w = z2 + z3 * v2;
      float t = tau1 * w;
      z23 = __builtin_fmaf(-tau1, w, z2);
      z33 = __builtin_fmaf(v2, -t, z3);
    }
  }

  // frames = vecs^T
  o[0] = z11; o[1] = z21; o[2] = z31;
  o[3] = z12; o[4] = z22; o[5] = z32;
  o[6] = z13; o[7] = z23; o[8] = z33;
}

// ---------------------------------------------------------------------------
// Tiled single kernel: 256 threads / 64 nodes per block.
//   sev[node*193 + slot*3 + c] : conflict-free both phases (193%32==1:
//   stage-2 lane n at fixed (j,c) hits bank (n+const)%32 -> 2-way, free).
//   Stage 1: 16 gather iterations (4096 edges / 256 threads).
//   Stage 2: wave 0 only, ALL 64 lanes active (minimum issue volume:
//   512 waves x S_union total), register-resident solver.
// ---------------------------------------------------------------------------
#define NODES_PER_BLOCK 64
#define NODE_STRIDE     193   /* 64*3 + 1 pad */

struct __attribute__((aligned(4))) f3 { float x, y, z; };

__global__ void __launch_bounds__(256)
pca_frames_tiled_kernel(const float* __restrict__ pos,
                        const int*   __restrict__ esrc,
                        const int*   __restrict__ nn,
                        float*       __restrict__ out,
                        int n)
{
#pragma clang fp contract(off)
  __shared__ float sev[NODES_PER_BLOCK * NODE_STRIDE];          // 49408 B

  const int tid   = threadIdx.x;
  const int node0 = blockIdx.x * NODES_PER_BLOCK;

  // ---- Stage 1: cooperative gather of this block's 64*64 edges ----
  const int ebase = blockIdx.x * (NODES_PER_BLOCK * 64);
  #pragma unroll
  for (int q = 0; q < (NODES_PER_BLOCK * 64) / 256; ++q) {
    int eb  = q * 256 + tid;
    int n_b = eb >> 6;          // wave-uniform
    int j   = eb & 63;
    int i   = node0 + n_b;
    int s   = esrc[ebase + eb];
    f3 ps   = *reinterpret_cast<const f3*>(pos + 3 * s);   // packed 12B gather
    // dst pos reads are wave-uniform (broadcast); rounding identical: rn(a-b)
    float dx = ps.x - pos[3 * i + 0];
    float dy = ps.y - pos[3 * i + 1];
    float dz = ps.z - pos[3 * i + 2];
    float* row = sev + n_b * NODE_STRIDE + 3 * j;
    row[0] = dx;
    row[1] = dy;
    row[2] = dz;
  }

  __syncthreads();

  // ---- Stage 2: wave 0, 64 lanes, one node per lane ----
  if (tid < 64) {
    int i = node0 + tid;
    float* o = out + (size_t)i * 9;

    if (nn[i] <= 1) {
      #pragma unroll
      for (int j = 0; j < 9; ++j) o[j] = 0.0f;
      return;
    }

    const float* row = sev + tid * NODE_STRIDE;
    float c00 = 0.0f, c01 = 0.0f, c02 = 0.0f, c11 = 0.0f, c12 = 0.0f, c22 = 0.0f;
    // EXACT sequential edge order, EXACT rounding (validated).
    for (int j = 0; j < 64; ++j) {
      float dx = row[3 * j + 0];
      float dy = row[3 * j + 1];
      float dz = row[3 * j + 2];
      c00 = c00 + dx * dx;
      c01 = c01 + dx * dy;
      c02 = c02 + dx * dz;
      c11 = c11 + dy * dy;
      c12 = c12 + dy * dz;
      c22 = c22 + dz * dz;
    }

    eig_frames_reg(c00, c01, c02, c11, c12, c22, o);
  }
}

// ---------------------------------------------------------------------------
// Fallback (unexpected shapes): validated fused structure, register solver.
// ---------------------------------------------------------------------------
__global__ void __launch_bounds__(64)
pca_frames_fused_kernel(const float* __restrict__ pos,
                        const int*   __restrict__ esrc,
                        const int*   __restrict__ nn,
                        float*       __restrict__ out,
                        int n, int k)
{
#pragma clang fp contract(off)
  int i = blockIdx.x * blockDim.x + threadIdx.x;
  if (i >= n) return;
  float* o = out + (size_t)i * 9;

  if (nn[i] <= 1) {
    #pragma unroll
    for (int j = 0; j < 9; ++j) o[j] = 0.0f;
    return;
  }

  float px = pos[3 * i + 0], py = pos[3 * i + 1], pz = pos[3 * i + 2];
  float c00 = 0.0f, c01 = 0.0f, c02 = 0.0f, c11 = 0.0f, c12 = 0.0f, c22 = 0.0f;
  const int* ep = esrc + (size_t)i * k;
  for (int j = 0; j < k; ++j) {
    int sidx = ep[j];
    float dx = pos[3 * sidx + 0] - px;
    float dy = pos[3 * sidx + 1] - py;
    float dz = pos[3 * sidx + 2] - pz;
    c00 = c00 + dx * dx;
    c01 = c01 + dx * dy;
    c02 = c02 + dx * dz;
    c11 = c11 + dy * dy;
    c12 = c12 + dy * dz;
    c22 = c22 + dz * dz;
  }

  eig_frames_reg(c00, c01, c02, c11, c12, c22, o);
}

extern "C" void kernel_launch(void* const* d_in, const int* in_sizes, int n_in,
                              void* d_out, int out_size, void* d_ws, size_t ws_size,
                              hipStream_t stream) {
  const float* pos  = (const float*)d_in[0];
  const int*   esrc = (const int*)d_in[1];
  // d_in[2] = edge_dst: unused (layout is repeat(arange(n), k) by construction)
  const int*   nn   = (const int*)d_in[3];
  float*       out  = (float*)d_out;

  int n = in_sizes[0] / 3;
  if (n <= 0) return;
  int k = in_sizes[1] / n;

  if (k == 64 && (n % NODES_PER_BLOCK) == 0) {
    hipLaunchKernelGGL(pca_frames_tiled_kernel, dim3(n / NODES_PER_BLOCK),
                       dim3(256), 0, stream, pos, esrc, nn, out, n);
  } else {
    const int block = 64;
    hipLaunchKernelGGL(pca_frames_fused_kernel, dim3((n + block - 1) / block),
                       dim3(block), 0, stream, pos, esrc, nn, out, n, k);
  }
}

// Round 9
// 95.358 us; speedup vs baseline: 1.3139x; 1.1512x over previous
//
#include <hip/hip_runtime.h>
#include <math.h>

// ---------------------------------------------------------------------------
// PCA local frames, round 9: statically-specialized register eigensolver.
//
// Issue model (validated r6-r8): per-wave stream S_union ~ const in active
// lanes L; total issue = (N/L)*S_union; stage-2 waves/SIMD = 32/L.  L=64
// minimizes issue (5.9 units) but runs solo dep-chains (46us, VALU 12.7%).
// Geometry exhausted -> shrink S_union: for n=3 the implicit-shift sweeps
// are only reachable at (l=1,m=3) [QL] / (l=3,m=1) [QR]; 2x2 paths have two
// arms; slasr columns are fixed.  All hot bodies rewritten as straight-line
// register code (no select fans).  Every FP operation is token-identical to
// the validated r2/r8 path -> bit-exact output.
//
// Round-3 lesson: no cross-kernel d_ws producer/consumer.  Single kernel.
// Sign-exactness (validated round 2): numpy ssyevd replica — SSYTD2(lower)
// -> SSTEQR('I') -> SLARF1F, OpenBLAS-FMA BLAS tails, contract-off
// elsewhere.  DO NOT reorder FP ops.
// ---------------------------------------------------------------------------

#pragma clang fp contract(off)

#define EPS_F32    5.9604645e-8f     /* SLAMCH('E') = 2^-24            */
#define SAFMIN_F32 1.17549435e-38f   /* SLAMCH('S') = 2^-126           */

__device__ __forceinline__ float lapy2f(float x, float y) {
#pragma clang fp contract(off)
  float xa = fabsf(x), ya = fabsf(y);
  float w = fmaxf(xa, ya);
  float z = fminf(xa, ya);
  if (z == 0.0f) return w;
  float t = z / w;
  return w * sqrtf(1.0f + t * t);
}

// LAPACK >= 3.10 slartg (float32).
__device__ __forceinline__ void slartgf(float f, float g, float* c, float* s, float* r) {
#pragma clang fp contract(off)
  const float safmin = SAFMIN_F32;
  const float safmax = 8.50705917e37f;   // 1/safmin
  const float rtmin  = 1.08420217e-19f;  // sqrt(safmin)
  const float rtmax  = 6.52530446e18f;   // sqrt(safmax/2)
  if (g == 0.0f) { *c = 1.0f; *s = 0.0f; *r = f; return; }
  if (f == 0.0f) { *c = 0.0f; *s = copysignf(1.0f, g); *r = fabsf(g); return; }
  float f1 = fabsf(f), g1 = fabsf(g);
  if (f1 > rtmin && f1 < rtmax && g1 > rtmin && g1 < rtmax) {
    float d = sqrtf(f * f + g * g);
    *c = f1 / d;
    *r = copysignf(d, f);
    *s = g / (*r);
  } else {
    float u  = fminf(safmax, fmaxf(safmin, fmaxf(f1, g1)));
    float fs = f / u, gs = g / u;
    float d  = sqrtf(fs * fs + gs * gs);
    *c = fabsf(fs) / d;
    float rr = copysignf(d, f);
    *s = gs / rr;
    *r = rr * u;
  }
}

// LAPACK slaev2 (float32), verbatim transcription.
__device__ __forceinline__ void slaev2f(float a, float b, float c,
                                        float* rt1, float* rt2,
                                        float* cs1, float* sn1) {
#pragma clang fp contract(off)
  float sm  = a + c;
  float df  = a - c;
  float adf = fabsf(df);
  float tb  = b + b;
  float ab  = fabsf(tb);
  float acmx, acmn;
  if (fabsf(a) > fabsf(c)) { acmx = a; acmn = c; } else { acmx = c; acmn = a; }
  float rt;
  if (adf > ab)      { float t = ab / adf; rt = adf * sqrtf(1.0f + t * t); }
  else if (adf < ab) { float t = adf / ab; rt = ab  * sqrtf(1.0f + t * t); }
  else               { rt = ab * sqrtf(2.0f); }
  int sgn1;
  if (sm < 0.0f) {
    *rt1 = 0.5f * (sm - rt); sgn1 = -1;
    *rt2 = (acmx / *rt1) * acmn - (b / *rt1) * b;
  } else if (sm > 0.0f) {
    *rt1 = 0.5f * (sm + rt); sgn1 = 1;
    *rt2 = (acmx / *rt1) * acmn - (b / *rt1) * b;
  } else {
    *rt1 = 0.5f * rt; *rt2 = -0.5f * rt; sgn1 = 1;
  }
  int sgn2; float cs;
  if (df >= 0.0f) { cs = df + rt; sgn2 = 1; }
  else            { cs = df - rt; sgn2 = -1; }
  float acs = fabsf(cs);
  if (acs > ab) {
    float ct = -tb / cs;
    *sn1 = 1.0f / sqrtf(1.0f + ct * ct);
    *cs1 = ct * (*sn1);
  } else {
    if (ab == 0.0f) { *cs1 = 1.0f; *sn1 = 0.0f; }
    else {
      float tn = -cs / tb;
      *cs1 = 1.0f / sqrtf(1.0f + tn * tn);
      *sn1 = tn * (*cs1);
    }
  }
  if (sgn1 == sgn2) { float tn = *cs1; *cs1 = -(*sn1); *sn1 = tn; }
}

// ---------------------------------------------------------------------------
// cov -> frames, all state in scalar registers; hot ssteqr bodies statically
// specialized for n=3.  FP-op sequence token-identical to validated path.
// ---------------------------------------------------------------------------
__device__ void eig_frames_reg(float c00, float c01, float c02,
                               float c11, float c12, float c22,
                               float* __restrict__ o) {
#pragma clang fp contract(off)
  // ---- SSYTD2, n=3, lower (one Householder), OpenBLAS-FMA BLAS model ----
  float d1, d2, d3, e1, e2, tau1, v2;
  {
    float a11 = c00, a21 = c01, a31 = c02, a22 = c11, a32 = c12, a33 = c22;
    float xnorm = fabsf(a31);
    if (xnorm == 0.0f) {
      tau1 = 0.0f; v2 = 0.0f;
      d1 = a11; d2 = a22; d3 = a33;
      e1 = a21; e2 = a32;
    } else {
      float py2  = lapy2f(a21, xnorm);
      float beta = -copysignf(py2, a21);
      tau1 = (beta - a21) / beta;
      v2   = a31 * (1.0f / (a21 - beta));
      float t2 = a32 * v2;
      float w1 = __builtin_fmaf(tau1, t2, tau1 * a22);
      float w2 = __builtin_fmaf(tau1 * v2, a33, tau1 * a32);
      float dot = __builtin_fmaf(v2, w2, w1);
      float ac = (-0.5f * tau1) * dot;
      w1 = w1 + ac;
      w2 = __builtin_fmaf(ac, v2, w2);
      float A11 = a22 - w1;
      A11 = A11 - w1;
      float A21 = a32 - w2;
      A21 = __builtin_fmaf(-w1, v2, A21);
      float A33 = __builtin_fmaf(-v2, w2, a33);
      A33 = __builtin_fmaf(-w2, v2, A33);
      d1 = a11; d2 = A11; d3 = A33;
      e1 = beta; e2 = A21;
    }
  }

  // ---- SSTEQR('I'), n=3, register-resident, specialized ----
  float z11 = 1.0f, z12 = 0.0f, z13 = 0.0f;
  float z21 = 0.0f, z22 = 1.0f, z23 = 0.0f;
  float z31 = 0.0f, z32 = 0.0f, z33 = 1.0f;
  float wc0, wc1, ws0, ws1;

#define DGET(i)    ((i) == 1 ? d1 : (i) == 2 ? d2 : d3)
#define DSET(i,v)  do { float _t = (v); if ((i) == 1) d1 = _t; else if ((i) == 2) d2 = _t; else d3 = _t; } while (0)
#define EGET(i)    ((i) == 1 ? e1 : e2)
#define ESET(i,v)  do { float _t = (v); if ((i) == 1) e1 = _t; else e2 = _t; } while (0)
#define ZGETC(r,c) ((r) == 1 ? ((c) == 1 ? z11 : (c) == 2 ? z12 : z13) \
                  : (r) == 2 ? ((c) == 1 ? z21 : (c) == 2 ? z22 : z23) \
                  :            ((c) == 1 ? z31 : (c) == 2 ? z32 : z33))
#define ZSETC(r,c,v) do { float _t = (v); \
    if ((r) == 1)      { if ((c) == 1) z11 = _t; else if ((c) == 2) z12 = _t; else z13 = _t; } \
    else if ((r) == 2) { if ((c) == 1) z21 = _t; else if ((c) == 2) z22 = _t; else z23 = _t; } \
    else               { if ((c) == 1) z31 = _t; else if ((c) == 2) z32 = _t; else z33 = _t; } } while (0)

  {
    const float eps    = EPS_F32;
    const float eps2   = eps * eps;
    const float safmin = SAFMIN_F32;
    const float ssfmax = sqrtf(8.50705917e37f) / 3.0f;
    const float ssfmin = sqrtf(safmin) / eps2;

    int   l1, l, m, lsv, lend, lendsv, iscale;
    const int nmaxit = 90;
    int   jtot = 0;
    float anorm, p, g, r, rt1, rt2, rc, rs, f, b, t;

    l1 = 1;

L10:
    if (l1 > 3) goto L160;
    if (l1 > 1) ESET(l1 - 1, 0.0f);
    if (l1 <= 2) {
      for (m = l1; m <= 2; m++) {
        float tst = fabsf(EGET(m));
        if (tst == 0.0f) goto L30;
        if (tst <= (sqrtf(fabsf(DGET(m))) * sqrtf(fabsf(DGET(m + 1)))) * eps) {
          ESET(m, 0.0f);
          goto L30;
        }
      }
    }
    m = 3;
L30:
    l = l1; lsv = l; lend = m; lendsv = lend; l1 = m + 1;
    if (lend == l) goto L10;

    // anorm = slanst('M', ...)
    anorm = 0.0f;
    for (int q = l; q <= lend; q++)     anorm = fmaxf(anorm, fabsf(DGET(q)));
    for (int q = l; q <= lend - 1; q++) anorm = fmaxf(anorm, fabsf(EGET(q)));
    iscale = 0;
    if (anorm == 0.0f) goto L10;
    if (anorm > ssfmax) {
      iscale = 1;
      float sc = ssfmax / anorm;
      for (int q = l; q <= lend; q++)     DSET(q, DGET(q) * sc);
      for (int q = l; q <= lend - 1; q++) ESET(q, EGET(q) * sc);
    } else if (anorm < ssfmin) {
      iscale = 2;
      float sc = ssfmin / anorm;
      for (int q = l; q <= lend; q++)     DSET(q, DGET(q) * sc);
      for (int q = l; q <= lend - 1; q++) ESET(q, EGET(q) * sc);
    }

    if (fabsf(DGET(lend)) < fabsf(DGET(l))) { lend = lsv; l = lendsv; }

    if (lend > l) {
      // ================= QL iteration =================
L40:
      if (l != lend) {
        // static m-search: reachable (l,lend): (1,3),(1,2),(2,3)
        if (l == 1) {
          float tst = e1 * e1;
          if (tst <= (eps2 * fabsf(d1)) * fabsf(d2) + safmin) { m = 1; goto L60; }
        }
        if (lend == 3) {
          float tst = e2 * e2;
          if (tst <= (eps2 * fabsf(d2)) * fabsf(d3) + safmin) { m = 2; goto L60; }
        }
      }
      m = lend;
L60:
      if (m < lend) ESET(m, 0.0f);
      p = DGET(l);
      if (m == l) goto L80;
      if (m == l + 1) {
        if (l == 1) {   // 2x2 on (d1,e1,d2), rotate cols (2,1)
          slaev2f(d1, e1, d2, &rt1, &rt2, &rc, &rs);
          t = z12; z12 = rc * t - rs * z11; z11 = rs * t + rc * z11;
          t = z22; z22 = rc * t - rs * z21; z21 = rs * t + rc * z21;
          t = z32; z32 = rc * t - rs * z31; z31 = rs * t + rc * z31;
          d1 = rt1; d2 = rt2; e1 = 0.0f;
        } else {        // l == 2: 2x2 on (d2,e2,d3), rotate cols (3,2)
          slaev2f(d2, e2, d3, &rt1, &rt2, &rc, &rs);
          t = z13; z13 = rc * t - rs * z12; z12 = rs * t + rc * z12;
          t = z23; z23 = rc * t - rs * z22; z22 = rs * t + rc * z22;
          t = z33; z33 = rc * t - rs * z32; z32 = rs * t + rc * z32;
          d2 = rt1; d3 = rt2; e2 = 0.0f;
        }
        l += 2;
        if (l <= lend) goto L40;
        goto L140;
      }
      // implicit-shift sweep — only reachable with l==1, m==3 (static)
      if (jtot == nmaxit) goto L140;
      jtot++;
      g = (d2 - p) / (2.0f * e1);
      r = lapy2f(g, 1.0f);
      g = d3 - p + (e1 / (g + copysignf(r, g)));
      rs = 1.0f; rc = 1.0f; p = 0.0f;
      // i = 2
      f = rs * e2;
      b = rc * e2;
      slartgf(g, f, &rc, &rs, &r);
      g = d3 - p;
      r = (d2 - g) * rs + 2.0f * rc * b;
      p = rs * r;
      d3 = g + p;
      g = rc * r - b;
      wc1 = rc; ws1 = -rs;
      // i = 1
      f = rs * e1;
      b = rc * e1;
      slartgf(g, f, &rc, &rs, &r);
      e2 = r;
      g = d2 - p;
      r = (d1 - g) * rs + 2.0f * rc * b;
      p = rs * r;
      d2 = g + p;
      g = rc * r - b;
      wc0 = rc; ws0 = -rs;
      // slasr 'R','V','B': j=2 (wc1,ws1, cols 3,2) then j=1 (wc0,ws0, cols 2,1)
      if (wc1 != 1.0f || ws1 != 0.0f) {
        t = z13; z13 = wc1 * t - ws1 * z12; z12 = ws1 * t + wc1 * z12;
        t = z23; z23 = wc1 * t - ws1 * z22; z22 = ws1 * t + wc1 * z22;
        t = z33; z33 = wc1 * t - ws1 * z32; z32 = ws1 * t + wc1 * z32;
      }
      if (wc0 != 1.0f || ws0 != 0.0f) {
        t = z12; z12 = wc0 * t - ws0 * z11; z11 = ws0 * t + wc0 * z11;
        t = z22; z22 = wc0 * t - ws0 * z21; z21 = ws0 * t + wc0 * z21;
        t = z32; z32 = wc0 * t - ws0 * z31; z31 = ws0 * t + wc0 * z31;
      }
      d1 = d1 - p;
      e1 = g;
      goto L40;
L80:
      DSET(l, p);
      l++;
      if (l <= lend) goto L40;
      goto L140;
    } else {
      // ================= QR iteration =================
L90:
      if (l != lend) {
        // static m-search: reachable (l,lend): (3,1),(3,2),(2,1)
        if (l == 3) {
          float tst = e2 * e2;
          if (tst <= (eps2 * fabsf(d3)) * fabsf(d2) + safmin) { m = 3; goto L110; }
        }
        if (lend == 1) {
          float tst = e1 * e1;
          if (tst <= (eps2 * fabsf(d2)) * fabsf(d1) + safmin) { m = 2; goto L110; }
        }
      }
      m = lend;
L110:
      if (m > lend) ESET(m - 1, 0.0f);
      p = DGET(l);
      if (m == l) goto L130;
      if (m == l - 1) {
        if (l == 2) {   // 2x2 on (d1,e1,d2), rotate 'F' cols (2,1)
          slaev2f(d1, e1, d2, &rt1, &rt2, &rc, &rs);
          t = z12; z12 = rc * t - rs * z11; z11 = rs * t + rc * z11;
          t = z22; z22 = rc * t - rs * z21; z21 = rs * t + rc * z21;
          t = z32; z32 = rc * t - rs * z31; z31 = rs * t + rc * z31;
          d1 = rt1; d2 = rt2; e1 = 0.0f;
        } else {        // l == 3 (m=2): 2x2 on (d2,e2,d3), rotate cols (3,2)
          slaev2f(d2, e2, d3, &rt1, &rt2, &rc, &rs);
          t = z13; z13 = rc * t - rs * z12; z12 = rs * t + rc * z12;
          t = z23; z23 = rc * t - rs * z22; z22 = rs * t + rc * z22;
          t = z33; z33 = rc * t - rs * z32; z32 = rs * t + rc * z32;
          d2 = rt1; d3 = rt2; e2 = 0.0f;
        }
        l -= 2;
        if (l >= lend) goto L90;
        goto L140;
      }
      // implicit-shift sweep — only reachable with l==3, m==1 (static)
      if (jtot == nmaxit) goto L140;
      jtot++;
      g = (d2 - p) / (2.0f * e2);
      r = lapy2f(g, 1.0f);
      g = d1 - p + (e2 / (g + copysignf(r, g)));
      rs = 1.0f; rc = 1.0f; p = 0.0f;
      // i = 1
      f = rs * e1;
      b = rc * e1;
      slartgf(g, f, &rc, &rs, &r);
      g = d1 - p;
      r = (d2 - g) * rs + 2.0f * rc * b;
      p = rs * r;
      d1 = g + p;
      g = rc * r - b;
      wc0 = rc; ws0 = rs;
      // i = 2
      f = rs * e2;
      b = rc * e2;
      slartgf(g, f, &rc, &rs, &r);
      e1 = r;
      g = d2 - p;
      r = (d3 - g) * rs + 2.0f * rc * b;
      p = rs * r;
      d2 = g + p;
      g = rc * r - b;
      wc1 = rc; ws1 = rs;
      // slasr 'R','V','F': j=1 (wc0,ws0, cols 2,1) then j=2 (wc1,ws1, cols 3,2)
      if (wc0 != 1.0f || ws0 != 0.0f) {
        t = z12; z12 = wc0 * t - ws0 * z11; z11 = ws0 * t + wc0 * z11;
        t = z22; z22 = wc0 * t - ws0 * z21; z21 = ws0 * t + wc0 * z21;
        t = z32; z32 = wc0 * t - ws0 * z31; z31 = ws0 * t + wc0 * z31;
      }
      if (wc1 != 1.0f || ws1 != 0.0f) {
        t = z13; z13 = wc1 * t - ws1 * z12; z12 = ws1 * t + wc1 * z12;
        t = z23; z23 = wc1 * t - ws1 * z22; z22 = ws1 * t + wc1 * z22;
        t = z33; z33 = wc1 * t - ws1 * z32; z32 = ws1 * t + wc1 * z32;
      }
      d3 = d3 - p;
      e2 = g;
      goto L90;
L130:
      DSET(l, p);
      l--;
      if (l >= lend) goto L90;
      goto L140;
    }

L140:
    if (iscale == 1) {
      float sc = anorm / ssfmax;
      for (int q = lsv; q <= lendsv; q++)     DSET(q, DGET(q) * sc);
      for (int q = lsv; q <= lendsv - 1; q++) ESET(q, EGET(q) * sc);
    } else if (iscale == 2) {
      float sc = anorm / ssfmin;
      for (int q = lsv; q <= lendsv; q++)     DSET(q, DGET(q) * sc);
      for (int q = lsv; q <= lendsv - 1; q++) ESET(q, EGET(q) * sc);
    }
    if (jtot < nmaxit) goto L10;
    goto L160;

L160:
    // ascending selection sort with column swaps (ssteqr tail, icompz>0)
    for (int ii = 2; ii <= 3; ii++) {
      int i = ii - 1, kk = i;
      p = DGET(i);
      for (int j = ii; j <= 3; j++) {
        if (DGET(j) < p) { kk = j; p = DGET(j); }
      }
      if (kk != i) {
        DSET(kk, DGET(i));
        DSET(i, p);
        #pragma unroll
        for (int row = 1; row <= 3; row++) {
          float tt = ZGETC(row, i);
          ZSETC(row, i, ZGETC(row, kk));
          ZSETC(row, kk, tt);
        }
      }
    }
  }

#undef DGET
#undef DSET
#undef EGET
#undef ESET
#undef ZGETC
#undef ZSETC

  // ---- SORM2R / SLARF1F: rows 2..3 of Z, u = (0, 1, v2) ----
  if (tau1 != 0.0f) {
    {
      float z2 = z21, z3 = z31;
      float w = z2 + z3 * v2;
      float t = tau1 * w;
      z21 = __builtin_fmaf(-tau1, w, z2);
      z31 = __builtin_fmaf(v2, -t, z3);
    }
    {
      float z2 = z22, z3 = z32;
      float w = z2 + z3 * v2;
      float t = tau1 * w;
      z22 = __builtin_fmaf(-tau1, w, z2);
      z32 = __builtin_fmaf(v2, -t, z3);
    }
    {
      float z2 = z23, z3 = z33;
      float w = z2 + z3 * v2;
      float t = tau1 * w;
      z23 = __builtin_fmaf(-tau1, w, z2);
      z33 = __builtin_fmaf(v2, -t, z3);
    }
  }

  // frames = vecs^T
  o[0] = z11; o[1] = z21; o[2] = z31;
  o[3] = z12; o[4] = z22; o[5] = z32;
  o[6] = z13; o[7] = z23; o[8] = z33;
}

// ---------------------------------------------------------------------------
// Tiled single kernel: 256 threads / 64 nodes per block (r8 geometry — the
// measured optimum of the L-tradeoff: L=64 minimizes total issue).
//   sev[node*193 + slot*3 + c] : conflict-free both phases.
// ---------------------------------------------------------------------------
#define NODES_PER_BLOCK 64
#define NODE_STRIDE     193   /* 64*3 + 1 pad */

struct __attribute__((aligned(4))) f3 { float x, y, z; };

__global__ void __launch_bounds__(256)
pca_frames_tiled_kernel(const float* __restrict__ pos,
                        const int*   __restrict__ esrc,
                        const int*   __restrict__ nn,
                        float*       __restrict__ out,
                        int n)
{
#pragma clang fp contract(off)
  __shared__ float sev[NODES_PER_BLOCK * NODE_STRIDE];          // 49408 B

  const int tid   = threadIdx.x;
  const int node0 = blockIdx.x * NODES_PER_BLOCK;

  // ---- Stage 1: cooperative gather of this block's 64*64 edges ----
  const int ebase = blockIdx.x * (NODES_PER_BLOCK * 64);
  #pragma unroll
  for (int q = 0; q < (NODES_PER_BLOCK * 64) / 256; ++q) {
    int eb  = q * 256 + tid;
    int n_b = eb >> 6;          // wave-uniform
    int j   = eb & 63;
    int i   = node0 + n_b;
    int s   = esrc[ebase + eb];
    f3 ps   = *reinterpret_cast<const f3*>(pos + 3 * s);   // packed 12B gather
    float dx = ps.x - pos[3 * i + 0];
    float dy = ps.y - pos[3 * i + 1];
    float dz = ps.z - pos[3 * i + 2];
    float* row = sev + n_b * NODE_STRIDE + 3 * j;
    row[0] = dx;
    row[1] = dy;
    row[2] = dz;
  }

  __syncthreads();

  // ---- Stage 2: wave 0, 64 lanes, one node per lane ----
  if (tid < 64) {
    int i = node0 + tid;
    float* o = out + (size_t)i * 9;

    if (nn[i] <= 1) {
      #pragma unroll
      for (int j = 0; j < 9; ++j) o[j] = 0.0f;
      return;
    }

    const float* row = sev + tid * NODE_STRIDE;
    float c00 = 0.0f, c01 = 0.0f, c02 = 0.0f, c11 = 0.0f, c12 = 0.0f, c22 = 0.0f;
    // EXACT sequential edge order, EXACT rounding (validated).
    for (int j = 0; j < 64; ++j) {
      float dx = row[3 * j + 0];
      float dy = row[3 * j + 1];
      float dz = row[3 * j + 2];
      c00 = c00 + dx * dx;
      c01 = c01 + dx * dy;
      c02 = c02 + dx * dz;
      c11 = c11 + dy * dy;
      c12 = c12 + dy * dz;
      c22 = c22 + dz * dz;
    }

    eig_frames_reg(c00, c01, c02, c11, c12, c22, o);
  }
}

// ---------------------------------------------------------------------------
// Fallback (unexpected shapes): validated fused structure, register solver.
// ---------------------------------------------------------------------------
__global__ void __launch_bounds__(64)
pca_frames_fused_kernel(const float* __restrict__ pos,
                        const int*   __restrict__ esrc,
                        const int*   __restrict__ nn,
                        float*       __restrict__ out,
                        int n, int k)
{
#pragma clang fp contract(off)
  int i = blockIdx.x * blockDim.x + threadIdx.x;
  if (i >= n) return;
  float* o = out + (size_t)i * 9;

  if (nn[i] <= 1) {
    #pragma unroll
    for (int j = 0; j < 9; ++j) o[j] = 0.0f;
    return;
  }

  float px = pos[3 * i + 0], py = pos[3 * i + 1], pz = pos[3 * i + 2];
  float c00 = 0.0f, c01 = 0.0f, c02 = 0.0f, c11 = 0.0f, c12 = 0.0f, c22 = 0.0f;
  const int* ep = esrc + (size_t)i * k;
  for (int j = 0; j < k; ++j) {
    int sidx = ep[j];
    float dx = pos[3 * sidx + 0] - px;
    float dy = pos[3 * sidx + 1] - py;
    float dz = pos[3 * sidx + 2] - pz;
    c00 = c00 + dx * dx;
    c01 = c01 + dx * dy;
    c02 = c02 + dx * dz;
    c11 = c11 + dy * dy;
    c12 = c12 + dy * dz;
    c22 = c22 + dz * dz;
  }

  eig_frames_reg(c00, c01, c02, c11, c12, c22, o);
}

extern "C" void kernel_launch(void* const* d_in, const int* in_sizes, int n_in,
                              void* d_out, int out_size, void* d_ws, size_t ws_size,
                              hipStream_t stream) {
  const float* pos  = (const float*)d_in[0];
  const int*   esrc = (const int*)d_in[1];
  // d_in[2] = edge_dst: unused (layout is repeat(arange(n), k) by construction)
  const int*   nn   = (const int*)d_in[3];
  float*       out  = (float*)d_out;

  int n = in_sizes[0] / 3;
  if (n <= 0) return;
  int k = in_sizes[1] / n;

  if (k == 64 && (n % NODES_PER_BLOCK) == 0) {
    hipLaunchKernelGGL(pca_frames_tiled_kernel, dim3(n / NODES_PER_BLOCK),
                       dim3(256), 0, stream, pos, esrc, nn, out, n);
  } else {
    const int block = 64;
    hipLaunchKernelGGL(pca_frames_fused_kernel, dim3((n + block - 1) / block),
                       dim3(block), 0, stream, pos, esrc, nn, out, n, k);
  }
}

// Round 10
// 89.572 us; speedup vs baseline: 1.3987x; 1.0646x over previous
//
#include <hip/hip_runtime.h>
#include <math.h>

// ---------------------------------------------------------------------------
// PCA local frames, round 10: state-machine eigensolver with arm sharing.
//
// Issue model (validated r6-r9): solver wave executes the exec-mask UNION of
// all lanes' arms per outer iteration.  r9's union ran both 2x2 bodies + QL
// sweep + QR sweep every iteration.  This round dispatches per-lane states
// in a wave loop and merges: 4 two-by-two sites -> 2 shared states; QL/QR
// sweep and check states -> 1 each via the index mirror a_i=d_{4-i},
// b_i=e_{3-i}, z-cols 1<->3 (rotation forms verified bitwise-equivalent:
// negation/add-commutation are exact).  Sort+SLARF+store run once after the
// loop in full lockstep.  NO FP op added/moved/reordered -> bit-exact.
//
// Round-3 lesson: no cross-kernel d_ws producer/consumer.  Single kernel.
// Sign-exactness (validated round 2): numpy ssyevd replica — SSYTD2(lower)
// -> SSTEQR('I') -> SLARF1F, OpenBLAS-FMA BLAS tails, contract-off
// elsewhere.  DO NOT reorder FP ops.
// ---------------------------------------------------------------------------

#pragma clang fp contract(off)

#define EPS_F32    5.9604645e-8f     /* SLAMCH('E') = 2^-24            */
#define SAFMIN_F32 1.17549435e-38f   /* SLAMCH('S') = 2^-126           */

__device__ __forceinline__ float lapy2f(float x, float y) {
#pragma clang fp contract(off)
  float xa = fabsf(x), ya = fabsf(y);
  float w = fmaxf(xa, ya);
  float z = fminf(xa, ya);
  if (z == 0.0f) return w;
  float t = z / w;
  return w * sqrtf(1.0f + t * t);
}

// LAPACK >= 3.10 slartg (float32).
__device__ __forceinline__ void slartgf(float f, float g, float* c, float* s, float* r) {
#pragma clang fp contract(off)
  const float safmin = SAFMIN_F32;
  const float safmax = 8.50705917e37f;   // 1/safmin
  const float rtmin  = 1.08420217e-19f;  // sqrt(safmin)
  const float rtmax  = 6.52530446e18f;   // sqrt(safmax/2)
  if (g == 0.0f) { *c = 1.0f; *s = 0.0f; *r = f; return; }
  if (f == 0.0f) { *c = 0.0f; *s = copysignf(1.0f, g); *r = fabsf(g); return; }
  float f1 = fabsf(f), g1 = fabsf(g);
  if (f1 > rtmin && f1 < rtmax && g1 > rtmin && g1 < rtmax) {
    float d = sqrtf(f * f + g * g);
    *c = f1 / d;
    *r = copysignf(d, f);
    *s = g / (*r);
  } else {
    float u  = fminf(safmax, fmaxf(safmin, fmaxf(f1, g1)));
    float fs = f / u, gs = g / u;
    float d  = sqrtf(fs * fs + gs * gs);
    *c = fabsf(fs) / d;
    float rr = copysignf(d, f);
    *s = gs / rr;
    *r = rr * u;
  }
}

// LAPACK slaev2 (float32), verbatim transcription.
__device__ __forceinline__ void slaev2f(float a, float b, float c,
                                        float* rt1, float* rt2,
                                        float* cs1, float* sn1) {
#pragma clang fp contract(off)
  float sm  = a + c;
  float df  = a - c;
  float adf = fabsf(df);
  float tb  = b + b;
  float ab  = fabsf(tb);
  float acmx, acmn;
  if (fabsf(a) > fabsf(c)) { acmx = a; acmn = c; } else { acmx = c; acmn = a; }
  float rt;
  if (adf > ab)      { float t = ab / adf; rt = adf * sqrtf(1.0f + t * t); }
  else if (adf < ab) { float t = adf / ab; rt = ab  * sqrtf(1.0f + t * t); }
  else               { rt = ab * sqrtf(2.0f); }
  int sgn1;
  if (sm < 0.0f) {
    *rt1 = 0.5f * (sm - rt); sgn1 = -1;
    *rt2 = (acmx / *rt1) * acmn - (b / *rt1) * b;
  } else if (sm > 0.0f) {
    *rt1 = 0.5f * (sm + rt); sgn1 = 1;
    *rt2 = (acmx / *rt1) * acmn - (b / *rt1) * b;
  } else {
    *rt1 = 0.5f * rt; *rt2 = -0.5f * rt; sgn1 = 1;
  }
  int sgn2; float cs;
  if (df >= 0.0f) { cs = df + rt; sgn2 = 1; }
  else            { cs = df - rt; sgn2 = -1; }
  float acs = fabsf(cs);
  if (acs > ab) {
    float ct = -tb / cs;
    *sn1 = 1.0f / sqrtf(1.0f + ct * ct);
    *cs1 = ct * (*sn1);
  } else {
    if (ab == 0.0f) { *cs1 = 1.0f; *sn1 = 0.0f; }
    else {
      float tn = -cs / tb;
      *cs1 = 1.0f / sqrtf(1.0f + tn * tn);
      *sn1 = tn * (*cs1);
    }
  }
  if (sgn1 == sgn2) { float tn = *cs1; *cs1 = -(*sn1); *sn1 = tn; }
}

#define ST_SEG   0
#define ST_CHK   1
#define ST_X21   2
#define ST_X32   3
#define ST_SWP   4
#define ST_RESC  5
#define ST_DONE  6

// ---------------------------------------------------------------------------
// cov -> frames.  Register state; ssteqr as per-lane state machine with
// shared arms.  FP trajectory token-identical to validated r9 path.
// ---------------------------------------------------------------------------
__device__ void eig_frames_sm(float c00, float c01, float c02,
                              float c11, float c12, float c22,
                              float* __restrict__ o) {
#pragma clang fp contract(off)
  // ---- SSYTD2, n=3, lower (one Householder), OpenBLAS-FMA BLAS model ----
  float d1, d2, d3, e1, e2, tau1, v2;
  {
    float a11 = c00, a21 = c01, a31 = c02, a22 = c11, a32 = c12, a33 = c22;
    float xnorm = fabsf(a31);
    if (xnorm == 0.0f) {
      tau1 = 0.0f; v2 = 0.0f;
      d1 = a11; d2 = a22; d3 = a33;
      e1 = a21; e2 = a32;
    } else {
      float py2  = lapy2f(a21, xnorm);
      float beta = -copysignf(py2, a21);
      tau1 = (beta - a21) / beta;
      v2   = a31 * (1.0f / (a21 - beta));
      float t2 = a32 * v2;
      float w1 = __builtin_fmaf(tau1, t2, tau1 * a22);
      float w2 = __builtin_fmaf(tau1 * v2, a33, tau1 * a32);
      float dot = __builtin_fmaf(v2, w2, w1);
      float ac = (-0.5f * tau1) * dot;
      w1 = w1 + ac;
      w2 = __builtin_fmaf(ac, v2, w2);
      float A11 = a22 - w1;
      A11 = A11 - w1;
      float A21 = a32 - w2;
      A21 = __builtin_fmaf(-w1, v2, A21);
      float A33 = __builtin_fmaf(-v2, w2, a33);
      A33 = __builtin_fmaf(-w2, v2, A33);
      d1 = a11; d2 = A11; d3 = A33;
      e1 = beta; e2 = A21;
    }
  }

  float z11 = 1.0f, z12 = 0.0f, z13 = 0.0f;
  float z21 = 0.0f, z22 = 1.0f, z23 = 0.0f;
  float z31 = 0.0f, z32 = 0.0f, z33 = 1.0f;

#define DGET(i)    ((i) == 1 ? d1 : (i) == 2 ? d2 : d3)
#define DSET(i,v)  do { float _t = (v); if ((i) == 1) d1 = _t; else if ((i) == 2) d2 = _t; else d3 = _t; } while (0)
#define EGET(i)    ((i) == 1 ? e1 : e2)
#define ESET(i,v)  do { float _t = (v); if ((i) == 1) e1 = _t; else e2 = _t; } while (0)
// mirrored accessors: a_i = d at (dir ? i : 4-i); b_i = e at (dir ? i : 3-i)
#define AGET(i)    DGET(dirQL ? (i) : 4 - (i))
#define ASET(i,v)  DSET(dirQL ? (i) : 4 - (i), v)
#define BGET(i)    EGET(dirQL ? (i) : 3 - (i))
#define BSET(i,v)  ESET(dirQL ? (i) : 3 - (i), v)
#define ZGETC(r,c) ((r) == 1 ? ((c) == 1 ? z11 : (c) == 2 ? z12 : z13) \
                  : (r) == 2 ? ((c) == 1 ? z21 : (c) == 2 ? z22 : z23) \
                  :            ((c) == 1 ? z31 : (c) == 2 ? z32 : z33))
#define ZSETC(r,c,v) do { float _t = (v); \
    if ((r) == 1)      { if ((c) == 1) z11 = _t; else if ((c) == 2) z12 = _t; else z13 = _t; } \
    else if ((r) == 2) { if ((c) == 1) z21 = _t; else if ((c) == 2) z22 = _t; else z23 = _t; } \
    else               { if ((c) == 1) z31 = _t; else if ((c) == 2) z32 = _t; else z33 = _t; } } while (0)

  const float eps    = EPS_F32;
  const float eps2   = eps * eps;
  const float safmin = SAFMIN_F32;
  const float ssfmax = sqrtf(8.50705917e37f) / 3.0f;
  const float ssfmin = sqrtf(safmin) / eps2;
  const int   nmaxit = 90;

  int   st = ST_SEG, nst = ST_CHK;
  int   l1 = 1, lm = 1, lendm = 1, lsv = 1, lendsv = 1, iscale = 0, jtot = 0;
  bool  dirQL = true;
  float anorm = 0.0f, p = 0.0f;

  for (int it = 0; it < 600; ++it) {
    if (!__any(st != ST_DONE)) break;

    // ---------------- SEG: segment finding (L10/L30) ----------------
    if (st == ST_SEG) {
      for (int pass = 0; pass < 4 && st == ST_SEG; ++pass) {
        if (l1 > 3) { st = ST_DONE; break; }
        if (l1 > 1) ESET(l1 - 1, 0.0f);
        int m = 3;
        {
          bool found = false;
          if (l1 <= 2) {
            for (int mi = l1; mi <= 2 && !found; mi++) {
              float tst = fabsf(EGET(mi));
              if (tst == 0.0f) { m = mi; found = true; }
              else if (tst <= (sqrtf(fabsf(DGET(mi))) * sqrtf(fabsf(DGET(mi + 1)))) * eps) {
                ESET(mi, 0.0f); m = mi; found = true;
              }
            }
          }
        }
        int l = l1; lsv = l; int lend = m; lendsv = lend; l1 = m + 1;
        if (lend == l) continue;
        anorm = 0.0f;
        for (int q = l; q <= lend; q++)     anorm = fmaxf(anorm, fabsf(DGET(q)));
        for (int q = l; q <= lend - 1; q++) anorm = fmaxf(anorm, fabsf(EGET(q)));
        iscale = 0;
        if (anorm == 0.0f) continue;
        if (anorm > ssfmax) {
          iscale = 1;
          float sc = ssfmax / anorm;
          for (int q = l; q <= lend; q++)     DSET(q, DGET(q) * sc);
          for (int q = l; q <= lend - 1; q++) ESET(q, EGET(q) * sc);
        } else if (anorm < ssfmin) {
          iscale = 2;
          float sc = ssfmin / anorm;
          for (int q = l; q <= lend; q++)     DSET(q, DGET(q) * sc);
          for (int q = l; q <= lend - 1; q++) ESET(q, EGET(q) * sc);
        }
        if (fabsf(DGET(lend)) < fabsf(DGET(l))) { int tt = l; l = lend; lend = tt; }
        dirQL = (lend > l);
        lm    = dirQL ? l : 4 - l;
        lendm = dirQL ? lend : 4 - lend;
        st = ST_CHK;
      }
    }

    // ---------------- CHK: mirrored L40/L90 m-search + dispatch ----------------
    if (st == ST_CHK) {
      int mm = lendm;
      {
        bool found = false;
        if (lm != lendm) {
          if (lm == 1) {
            float bb = BGET(1);
            float tst = bb * bb;
            if (tst <= (eps2 * fabsf(AGET(1))) * fabsf(AGET(2)) + safmin) { mm = 1; found = true; }
          }
          if (!found && lendm == 3) {
            float bb = BGET(2);
            float tst = bb * bb;
            if (tst <= (eps2 * fabsf(AGET(2))) * fabsf(AGET(3)) + safmin) { mm = 2; found = true; }
          }
        }
      }
      if (mm < lendm) BSET(mm, 0.0f);
      p = AGET(lm);
      if (mm == lm) {
        // deflate (L80/L130)
        ASET(lm, p); lm++;
        st = (lm <= lendm) ? ST_CHK : ST_RESC;
      } else if (mm == lm + 1) {
        int lo = dirQL ? lm : 4 - mm;        // real lower index of the 2x2
        lm += 2;
        nst = (lm <= lendm) ? ST_CHK : ST_RESC;
        st = (lo == 1) ? ST_X21 : ST_X32;
      } else {
        st = (jtot == nmaxit) ? ST_RESC : ST_SWP;
      }
    }

    // ---------------- X21: shared 2x2 on (d1,e1,d2), rotate cols (2,1) ----------------
    if (st == ST_X21) {
      float rt1, rt2, rc, rs, t;
      slaev2f(d1, e1, d2, &rt1, &rt2, &rc, &rs);
      t = z12; z12 = rc * t - rs * z11; z11 = rs * t + rc * z11;
      t = z22; z22 = rc * t - rs * z21; z21 = rs * t + rc * z21;
      t = z32; z32 = rc * t - rs * z31; z31 = rs * t + rc * z31;
      d1 = rt1; d2 = rt2; e1 = 0.0f;
      st = nst;
    }

    // ---------------- X32: shared 2x2 on (d2,e2,d3), rotate cols (3,2) ----------------
    if (st == ST_X32) {
      float rt1, rt2, rc, rs, t;
      slaev2f(d2, e2, d3, &rt1, &rt2, &rc, &rs);
      t = z13; z13 = rc * t - rs * z12; z12 = rs * t + rc * z12;
      t = z23; z23 = rc * t - rs * z22; z22 = rs * t + rc * z22;
      t = z33; z33 = rc * t - rs * z32; z32 = rs * t + rc * z32;
      d2 = rt1; d3 = rt2; e2 = 0.0f;
      st = nst;
    }

    // ---------------- SWP: mirrored implicit-shift sweep ----------------
    if (st == ST_SWP) {
      jtot++;
      float a1 = dirQL ? d1 : d3;
      float a2 = d2;
      float a3 = dirQL ? d3 : d1;
      float b1 = dirQL ? e1 : e2;
      float b2 = dirQL ? e2 : e1;
      float g, r, rc, rs, f, b;
      g = (a2 - p) / (2.0f * b1);
      r = lapy2f(g, 1.0f);
      g = a3 - p + (b1 / (g + copysignf(r, g)));
      rs = 1.0f; rc = 1.0f; p = 0.0f;
      // step A (QL i=2 / QR i=1)
      f = rs * b2;
      b = rc * b2;
      slartgf(g, f, &rc, &rs, &r);
      g = a3 - p;
      r = (a2 - g) * rs + 2.0f * rc * b;
      p = rs * r;
      a3 = g + p;
      g = rc * r - b;
      float wcA = rc, rsA = rs;
      // step B (QL i=1 / QR i=2)
      f = rs * b1;
      b = rc * b1;
      slartgf(g, f, &rc, &rs, &r);
      b2 = r;
      g = a2 - p;
      r = (a1 - g) * rs + 2.0f * rc * b;
      p = rs * r;
      a2 = g + p;
      g = rc * r - b;
      float wcB = rc, rsB = rs;
      // rotation A on pair (hi = col(dir?3:1), lo = col2); canonical forms
      // bitwise-equal to QL's (ws=-rs) and QR's (ws=+rs) literal sequences.
      if (wcA != 1.0f || rsA != 0.0f) {
        {
          float hi = dirQL ? z13 : z11, lo = z12;
          float nh = wcA * hi + rsA * lo;
          float nl = wcA * lo - rsA * hi;
          if (dirQL) z13 = nh; else z11 = nh;
          z12 = nl;
        }
        {
          float hi = dirQL ? z23 : z21, lo = z22;
          float nh = wcA * hi + rsA * lo;
          float nl = wcA * lo - rsA * hi;
          if (dirQL) z23 = nh; else z21 = nh;
          z22 = nl;
        }
        {
          float hi = dirQL ? z33 : z31, lo = z32;
          float nh = wcA * hi + rsA * lo;
          float nl = wcA * lo - rsA * hi;
          if (dirQL) z33 = nh; else z31 = nh;
          z32 = nl;
        }
      }
      // rotation B on pair (hi = col2, lo = col(dir?1:3))
      if (wcB != 1.0f || rsB != 0.0f) {
        {
          float hi = z12, lo = dirQL ? z11 : z13;
          float nh = wcB * hi + rsB * lo;
          float nl = wcB * lo - rsB * hi;
          z12 = nh;
          if (dirQL) z11 = nl; else z13 = nl;
        }
        {
          float hi = z22, lo = dirQL ? z21 : z23;
          float nh = wcB * hi + rsB * lo;
          float nl = wcB * lo - rsB * hi;
          z22 = nh;
          if (dirQL) z21 = nl; else z23 = nl;
        }
        {
          float hi = z32, lo = dirQL ? z31 : z33;
          float nh = wcB * hi + rsB * lo;
          float nl = wcB * lo - rsB * hi;
          z32 = nh;
          if (dirQL) z31 = nl; else z33 = nl;
        }
      }
      a1 = a1 - p;
      b1 = g;
      // route back
      if (dirQL) { d1 = a1; d3 = a3; e1 = b1; e2 = b2; }
      else       { d3 = a1; d1 = a3; e2 = b1; e1 = b2; }
      d2 = a2;
      st = ST_CHK;
    }

    // ---------------- RESC: L140 rescale ----------------
    if (st == ST_RESC) {
      if (iscale == 1) {
        float sc = anorm / ssfmax;
        for (int q = lsv; q <= lendsv; q++)     DSET(q, DGET(q) * sc);
        for (int q = lsv; q <= lendsv - 1; q++) ESET(q, EGET(q) * sc);
      } else if (iscale == 2) {
        float sc = anorm / ssfmin;
        for (int q = lsv; q <= lendsv; q++)     DSET(q, DGET(q) * sc);
        for (int q = lsv; q <= lendsv - 1; q++) ESET(q, EGET(q) * sc);
      }
      st = (jtot < nmaxit) ? ST_SEG : ST_DONE;
    }
  }

  // ---------------- sort (L160) — lockstep, once ----------------
  {
    float p;
    for (int ii = 2; ii <= 3; ii++) {
      int i = ii - 1, kk = i;
      p = DGET(i);
      for (int j = ii; j <= 3; j++) {
        if (DGET(j) < p) { kk = j; p = DGET(j); }
      }
      if (kk != i) {
        DSET(kk, DGET(i));
        DSET(i, p);
        #pragma unroll
        for (int row = 1; row <= 3; row++) {
          float tt = ZGETC(row, i);
          ZSETC(row, i, ZGETC(row, kk));
          ZSETC(row, kk, tt);
        }
      }
    }
  }

#undef DGET
#undef DSET
#undef EGET
#undef ESET
#undef AGET
#undef ASET
#undef BGET
#undef BSET
#undef ZGETC
#undef ZSETC

  // ---- SORM2R / SLARF1F: rows 2..3 of Z, u = (0, 1, v2) ----
  if (tau1 != 0.0f) {
    {
      float z2 = z21, z3 = z31;
      float w = z2 + z3 * v2;
      float t = tau1 * w;
      z21 = __builtin_fmaf(-tau1, w, z2);
      z31 = __builtin_fmaf(v2, -t, z3);
    }
    {
      float z2 = z22, z3 = z32;
      float w = z2 + z3 * v2;
      float t = tau1 * w;
      z22 = __builtin_fmaf(-tau1, w, z2);
      z32 = __builtin_fmaf(v2, -t, z3);
    }
    {
      float z2 = z23, z3 = z33;
      float w = z2 + z3 * v2;
      float t = tau1 * w;
      z23 = __builtin_fmaf(-tau1, w, z2);
      z33 = __builtin_fmaf(v2, -t, z3);
    }
  }

  // frames = vecs^T
  o[0] = z11; o[1] = z21; o[2] = z31;
  o[3] = z12; o[4] = z22; o[5] = z32;
  o[6] = z13; o[7] = z23; o[8] = z33;
}

// ---------------------------------------------------------------------------
// Tiled single kernel: 256 threads / 64 nodes per block (measured-optimal
// L=64 geometry).  sev[node*193 + slot*3 + c]: conflict-free both phases.
// ---------------------------------------------------------------------------
#define NODES_PER_BLOCK 64
#define NODE_STRIDE     193   /* 64*3 + 1 pad */

struct __attribute__((aligned(4))) f3 { float x, y, z; };

__global__ void __launch_bounds__(256)
pca_frames_tiled_kernel(const float* __restrict__ pos,
                        const int*   __restrict__ esrc,
                        const int*   __restrict__ nn,
                        float*       __restrict__ out,
                        int n)
{
#pragma clang fp contract(off)
  __shared__ float sev[NODES_PER_BLOCK * NODE_STRIDE];          // 49408 B

  const int tid   = threadIdx.x;
  const int node0 = blockIdx.x * NODES_PER_BLOCK;

  // ---- Stage 1: cooperative gather of this block's 64*64 edges ----
  const int ebase = blockIdx.x * (NODES_PER_BLOCK * 64);
  #pragma unroll
  for (int q = 0; q < (NODES_PER_BLOCK * 64) / 256; ++q) {
    int eb  = q * 256 + tid;
    int n_b = eb >> 6;          // wave-uniform
    int j   = eb & 63;
    int i   = node0 + n_b;
    int s   = esrc[ebase + eb];
    f3 ps   = *reinterpret_cast<const f3*>(pos + 3 * s);   // packed 12B gather
    float dx = ps.x - pos[3 * i + 0];
    float dy = ps.y - pos[3 * i + 1];
    float dz = ps.z - pos[3 * i + 2];
    float* row = sev + n_b * NODE_STRIDE + 3 * j;
    row[0] = dx;
    row[1] = dy;
    row[2] = dz;
  }

  __syncthreads();

  // ---- Stage 2: wave 0, 64 lanes, one node per lane ----
  if (tid < 64) {
    int i = node0 + tid;
    float* o = out + (size_t)i * 9;

    if (nn[i] <= 1) {
      #pragma unroll
      for (int j = 0; j < 9; ++j) o[j] = 0.0f;
      return;
    }

    const float* row = sev + tid * NODE_STRIDE;
    float c00 = 0.0f, c01 = 0.0f, c02 = 0.0f, c11 = 0.0f, c12 = 0.0f, c22 = 0.0f;
    // EXACT sequential edge order, EXACT rounding (validated).
    for (int j = 0; j < 64; ++j) {
      float dx = row[3 * j + 0];
      float dy = row[3 * j + 1];
      float dz = row[3 * j + 2];
      c00 = c00 + dx * dx;
      c01 = c01 + dx * dy;
      c02 = c02 + dx * dz;
      c11 = c11 + dy * dy;
      c12 = c12 + dy * dz;
      c22 = c22 + dz * dz;
    }

    eig_frames_sm(c00, c01, c02, c11, c12, c22, o);
  }
}

// ---------------------------------------------------------------------------
// Fallback (unexpected shapes): validated fused structure, same solver.
// ---------------------------------------------------------------------------
__global__ void __launch_bounds__(64)
pca_frames_fused_kernel(const float* __restrict__ pos,
                        const int*   __restrict__ esrc,
                        const int*   __restrict__ nn,
                        float*       __restrict__ out,
                        int n, int k)
{
#pragma clang fp contract(off)
  int i = blockIdx.x * blockDim.x + threadIdx.x;
  if (i >= n) return;
  float* o = out + (size_t)i * 9;

  if (nn[i] <= 1) {
    #pragma unroll
    for (int j = 0; j < 9; ++j) o[j] = 0.0f;
    return;
  }

  float px = pos[3 * i + 0], py = pos[3 * i + 1], pz = pos[3 * i + 2];
  float c00 = 0.0f, c01 = 0.0f, c02 = 0.0f, c11 = 0.0f, c12 = 0.0f, c22 = 0.0f;
  const int* ep = esrc + (size_t)i * k;
  for (int j = 0; j < k; ++j) {
    int sidx = ep[j];
    float dx = pos[3 * sidx + 0] - px;
    float dy = pos[3 * sidx + 1] - py;
    float dz = pos[3 * sidx + 2] - pz;
    c00 = c00 + dx * dx;
    c01 = c01 + dx * dy;
    c02 = c02 + dx * dz;
    c11 = c11 + dy * dy;
    c12 = c12 + dy * dz;
    c22 = c22 + dz * dz;
  }

  eig_frames_sm(c00, c01, c02, c11, c12, c22, o);
}

extern "C" void kernel_launch(void* const* d_in, const int* in_sizes, int n_in,
                              void* d_out, int out_size, void* d_ws, size_t ws_size,
                              hipStream_t stream) {
  const float* pos  = (const float*)d_in[0];
  const int*   esrc = (const int*)d_in[1];
  // d_in[2] = edge_dst: unused (layout is repeat(arange(n), k) by construction)
  const int*   nn   = (const int*)d_in[3];
  float*       out  = (float*)d_out;

  int n = in_sizes[0] / 3;
  if (n <= 0) return;
  int k = in_sizes[1] / n;

  if (k == 64 && (n % NODES_PER_BLOCK) == 0) {
    hipLaunchKernelGGL(pca_frames_tiled_kernel, dim3(n / NODES_PER_BLOCK),
                       dim3(256), 0, stream, pos, esrc, nn, out, n);
  } else {
    const int block = 64;
    hipLaunchKernelGGL(pca_frames_fused_kernel, dim3((n + block - 1) / block),
                       dim3(block), 0, stream, pos, esrc, nn, out, n, k);
  }
}

// Round 11
// 87.314 us; speedup vs baseline: 1.4349x; 1.0259x over previous
//
#include <hip/hip_runtime.h>
#include <math.h>

// ---------------------------------------------------------------------------
// PCA local frames, round 11: state-machine solver, SEG specialized + 2x2
// states merged.
//
// Issue model (validated r6-r10): solver wave executes the exec-mask UNION
// of lanes' state bodies per dispatch iteration; total issue = 512 x S_union.
// r10 union ~= SEG(150, dynamic loops) + CHK + X21 + X32 + SWP + RESC.
// This round: (a) SEG straight-lined over its full (l,lend) domain
// {(1,2),(1,3),(2,3)} — fmax chains are exact so restructuring is bit-safe;
// (b) X21/X32 merged into one X22 state (shared slaev2, column-pair select;
// rotation form is the literal token sequence of both).  NO FP op added/
// moved/reordered on any trajectory -> bit-exact.
//
// Round-3 lesson: no cross-kernel d_ws producer/consumer.  Single kernel.
// Sign-exactness (validated round 2): numpy ssyevd replica — SSYTD2(lower)
// -> SSTEQR('I') -> SLARF1F, OpenBLAS-FMA BLAS tails, contract-off
// elsewhere.  DO NOT reorder FP ops.
// ---------------------------------------------------------------------------

#pragma clang fp contract(off)

#define EPS_F32    5.9604645e-8f     /* SLAMCH('E') = 2^-24            */
#define SAFMIN_F32 1.17549435e-38f   /* SLAMCH('S') = 2^-126           */

__device__ __forceinline__ float lapy2f(float x, float y) {
#pragma clang fp contract(off)
  float xa = fabsf(x), ya = fabsf(y);
  float w = fmaxf(xa, ya);
  float z = fminf(xa, ya);
  if (z == 0.0f) return w;
  float t = z / w;
  return w * sqrtf(1.0f + t * t);
}

// LAPACK >= 3.10 slartg (float32).
__device__ __forceinline__ void slartgf(float f, float g, float* c, float* s, float* r) {
#pragma clang fp contract(off)
  const float safmin = SAFMIN_F32;
  const float safmax = 8.50705917e37f;   // 1/safmin
  const float rtmin  = 1.08420217e-19f;  // sqrt(safmin)
  const float rtmax  = 6.52530446e18f;   // sqrt(safmax/2)
  if (g == 0.0f) { *c = 1.0f; *s = 0.0f; *r = f; return; }
  if (f == 0.0f) { *c = 0.0f; *s = copysignf(1.0f, g); *r = fabsf(g); return; }
  float f1 = fabsf(f), g1 = fabsf(g);
  if (f1 > rtmin && f1 < rtmax && g1 > rtmin && g1 < rtmax) {
    float d = sqrtf(f * f + g * g);
    *c = f1 / d;
    *r = copysignf(d, f);
    *s = g / (*r);
  } else {
    float u  = fminf(safmax, fmaxf(safmin, fmaxf(f1, g1)));
    float fs = f / u, gs = g / u;
    float d  = sqrtf(fs * fs + gs * gs);
    *c = fabsf(fs) / d;
    float rr = copysignf(d, f);
    *s = gs / rr;
    *r = rr * u;
  }
}

// LAPACK slaev2 (float32), verbatim transcription.
__device__ __forceinline__ void slaev2f(float a, float b, float c,
                                        float* rt1, float* rt2,
                                        float* cs1, float* sn1) {
#pragma clang fp contract(off)
  float sm  = a + c;
  float df  = a - c;
  float adf = fabsf(df);
  float tb  = b + b;
  float ab  = fabsf(tb);
  float acmx, acmn;
  if (fabsf(a) > fabsf(c)) { acmx = a; acmn = c; } else { acmx = c; acmn = a; }
  float rt;
  if (adf > ab)      { float t = ab / adf; rt = adf * sqrtf(1.0f + t * t); }
  else if (adf < ab) { float t = adf / ab; rt = ab  * sqrtf(1.0f + t * t); }
  else               { rt = ab * sqrtf(2.0f); }
  int sgn1;
  if (sm < 0.0f) {
    *rt1 = 0.5f * (sm - rt); sgn1 = -1;
    *rt2 = (acmx / *rt1) * acmn - (b / *rt1) * b;
  } else if (sm > 0.0f) {
    *rt1 = 0.5f * (sm + rt); sgn1 = 1;
    *rt2 = (acmx / *rt1) * acmn - (b / *rt1) * b;
  } else {
    *rt1 = 0.5f * rt; *rt2 = -0.5f * rt; sgn1 = 1;
  }
  int sgn2; float cs;
  if (df >= 0.0f) { cs = df + rt; sgn2 = 1; }
  else            { cs = df - rt; sgn2 = -1; }
  float acs = fabsf(cs);
  if (acs > ab) {
    float ct = -tb / cs;
    *sn1 = 1.0f / sqrtf(1.0f + ct * ct);
    *cs1 = ct * (*sn1);
  } else {
    if (ab == 0.0f) { *cs1 = 1.0f; *sn1 = 0.0f; }
    else {
      float tn = -cs / tb;
      *cs1 = 1.0f / sqrtf(1.0f + tn * tn);
      *sn1 = tn * (*cs1);
    }
  }
  if (sgn1 == sgn2) { float tn = *cs1; *cs1 = -(*sn1); *sn1 = tn; }
}

#define ST_SEG   0
#define ST_CHK   1
#define ST_X22   2
#define ST_SWP   3
#define ST_RESC  4
#define ST_DONE  5

// ---------------------------------------------------------------------------
// cov -> frames.  Register state; ssteqr as per-lane state machine with
// shared arms; SEG fully specialized.  FP trajectory token-identical to the
// validated r10 path.
// ---------------------------------------------------------------------------
__device__ void eig_frames_sm(float c00, float c01, float c02,
                              float c11, float c12, float c22,
                              float* __restrict__ o) {
#pragma clang fp contract(off)
  // ---- SSYTD2, n=3, lower (one Householder), OpenBLAS-FMA BLAS model ----
  float d1, d2, d3, e1, e2, tau1, v2;
  {
    float a11 = c00, a21 = c01, a31 = c02, a22 = c11, a32 = c12, a33 = c22;
    float xnorm = fabsf(a31);
    if (xnorm == 0.0f) {
      tau1 = 0.0f; v2 = 0.0f;
      d1 = a11; d2 = a22; d3 = a33;
      e1 = a21; e2 = a32;
    } else {
      float py2  = lapy2f(a21, xnorm);
      float beta = -copysignf(py2, a21);
      tau1 = (beta - a21) / beta;
      v2   = a31 * (1.0f / (a21 - beta));
      float t2 = a32 * v2;
      float w1 = __builtin_fmaf(tau1, t2, tau1 * a22);
      float w2 = __builtin_fmaf(tau1 * v2, a33, tau1 * a32);
      float dot = __builtin_fmaf(v2, w2, w1);
      float ac = (-0.5f * tau1) * dot;
      w1 = w1 + ac;
      w2 = __builtin_fmaf(ac, v2, w2);
      float A11 = a22 - w1;
      A11 = A11 - w1;
      float A21 = a32 - w2;
      A21 = __builtin_fmaf(-w1, v2, A21);
      float A33 = __builtin_fmaf(-v2, w2, a33);
      A33 = __builtin_fmaf(-w2, v2, A33);
      d1 = a11; d2 = A11; d3 = A33;
      e1 = beta; e2 = A21;
    }
  }

  float z11 = 1.0f, z12 = 0.0f, z13 = 0.0f;
  float z21 = 0.0f, z22 = 1.0f, z23 = 0.0f;
  float z31 = 0.0f, z32 = 0.0f, z33 = 1.0f;

#define DGET(i)    ((i) == 1 ? d1 : (i) == 2 ? d2 : d3)
#define DSET(i,v)  do { float _t = (v); if ((i) == 1) d1 = _t; else if ((i) == 2) d2 = _t; else d3 = _t; } while (0)
#define EGET(i)    ((i) == 1 ? e1 : e2)
#define ESET(i,v)  do { float _t = (v); if ((i) == 1) e1 = _t; else e2 = _t; } while (0)
// mirrored accessors: a_i = d at (dir ? i : 4-i); b_i = e at (dir ? i : 3-i)
#define AGET(i)    DGET(dirQL ? (i) : 4 - (i))
#define ASET(i,v)  DSET(dirQL ? (i) : 4 - (i), v)
#define BGET(i)    EGET(dirQL ? (i) : 3 - (i))
#define BSET(i,v)  ESET(dirQL ? (i) : 3 - (i), v)
#define ZGETC(r,c) ((r) == 1 ? ((c) == 1 ? z11 : (c) == 2 ? z12 : z13) \
                  : (r) == 2 ? ((c) == 1 ? z21 : (c) == 2 ? z22 : z23) \
                  :            ((c) == 1 ? z31 : (c) == 2 ? z32 : z33))
#define ZSETC(r,c,v) do { float _t = (v); \
    if ((r) == 1)      { if ((c) == 1) z11 = _t; else if ((c) == 2) z12 = _t; else z13 = _t; } \
    else if ((r) == 2) { if ((c) == 1) z21 = _t; else if ((c) == 2) z22 = _t; else z23 = _t; } \
    else               { if ((c) == 1) z31 = _t; else if ((c) == 2) z32 = _t; else z33 = _t; } } while (0)

  const float eps    = EPS_F32;
  const float eps2   = eps * eps;
  const float safmin = SAFMIN_F32;
  const float ssfmax = sqrtf(8.50705917e37f) / 3.0f;
  const float ssfmin = sqrtf(safmin) / eps2;
  const int   nmaxit = 90;

  int   st = ST_SEG, nst = ST_CHK, x2lo = 1;
  int   l1 = 1, lm = 1, lendm = 1, lsv = 1, lendsv = 1, iscale = 0, jtot = 0;
  bool  dirQL = true;
  float anorm = 0.0f, p = 0.0f;

  for (int it = 0; it < 600; ++it) {
    if (!__any(st != ST_DONE)) break;

    // ---------------- SEG: specialized segment finding (L10/L30) ----------------
    if (st == ST_SEG) {
      for (int pass = 0; pass < 4 && st == ST_SEG; ++pass) {
        if (l1 > 3) { st = ST_DONE; break; }
        if (l1 == 2) e1 = 0.0f;
        else if (l1 == 3) e2 = 0.0f;
        // m-search (static per l1):
        int m;
        if (l1 == 1) {
          float tst = fabsf(e1);
          if (tst == 0.0f) m = 1;
          else if (tst <= (sqrtf(fabsf(d1)) * sqrtf(fabsf(d2))) * eps) { e1 = 0.0f; m = 1; }
          else {
            float tst2 = fabsf(e2);
            if (tst2 == 0.0f) m = 2;
            else if (tst2 <= (sqrtf(fabsf(d2)) * sqrtf(fabsf(d3))) * eps) { e2 = 0.0f; m = 2; }
            else m = 3;
          }
        } else if (l1 == 2) {
          float tst2 = fabsf(e2);
          if (tst2 == 0.0f) m = 2;
          else if (tst2 <= (sqrtf(fabsf(d2)) * sqrtf(fabsf(d3))) * eps) { e2 = 0.0f; m = 2; }
          else m = 3;
        } else m = 3;

        int l = l1; lsv = l; int lend = m; lendsv = lend; l1 = m + 1;
        if (lend == l) continue;

        // anorm over the segment — fmax is exact, chain restructuring bit-safe.
        // shapes: (1,2),(1,3),(2,3)
        if (l == 1) {
          if (lend == 3)
            anorm = fmaxf(fmaxf(fmaxf(fabsf(d1), fabsf(d2)), fabsf(d3)),
                          fmaxf(fabsf(e1), fabsf(e2)));
          else
            anorm = fmaxf(fmaxf(fabsf(d1), fabsf(d2)), fabsf(e1));
        } else {
          anorm = fmaxf(fmaxf(fabsf(d2), fabsf(d3)), fabsf(e2));
        }
        iscale = 0;
        if (anorm == 0.0f) continue;
        if (anorm > ssfmax || anorm < ssfmin) {
          float sc;
          if (anorm > ssfmax) { iscale = 1; sc = ssfmax / anorm; }
          else                { iscale = 2; sc = ssfmin / anorm; }
          if (l == 1) {
            d1 = d1 * sc; d2 = d2 * sc; e1 = e1 * sc;
            if (lend == 3) { d3 = d3 * sc; e2 = e2 * sc; }
          } else {
            d2 = d2 * sc; d3 = d3 * sc; e2 = e2 * sc;
          }
        }
        // direction decision (static per shape)
        float dl = (l == 1) ? d1 : d2;
        float de = (lend == 3) ? d3 : d2;
        if (fabsf(de) < fabsf(dl)) { int tt = l; l = lend; lend = tt; }
        dirQL = (lend > l);
        lm    = dirQL ? l : 4 - l;
        lendm = dirQL ? lend : 4 - lend;
        st = ST_CHK;
      }
    }

    // ---------------- CHK: mirrored L40/L90 m-search + dispatch ----------------
    if (st == ST_CHK) {
      int mm = lendm;
      {
        bool found = false;
        if (lm != lendm) {
          if (lm == 1) {
            float bb = BGET(1);
            float tst = bb * bb;
            if (tst <= (eps2 * fabsf(AGET(1))) * fabsf(AGET(2)) + safmin) { mm = 1; found = true; }
          }
          if (!found && lendm == 3) {
            float bb = BGET(2);
            float tst = bb * bb;
            if (tst <= (eps2 * fabsf(AGET(2))) * fabsf(AGET(3)) + safmin) { mm = 2; found = true; }
          }
        }
      }
      if (mm < lendm) BSET(mm, 0.0f);
      p = AGET(lm);
      if (mm == lm) {
        // deflate (L80/L130)
        ASET(lm, p); lm++;
        st = (lm <= lendm) ? ST_CHK : ST_RESC;
      } else if (mm == lm + 1) {
        x2lo = dirQL ? lm : 4 - mm;          // real lower index of the 2x2
        lm += 2;
        nst = (lm <= lendm) ? ST_CHK : ST_RESC;
        st = ST_X22;
      } else {
        st = (jtot == nmaxit) ? ST_RESC : ST_SWP;
      }
    }

    // ---------------- X22: shared 2x2 (x2lo selects (d1,e1,d2) / (d2,e2,d3)) ----------------
    if (st == ST_X22) {
      float rt1, rt2, rc, rs;
      float aa = (x2lo == 1) ? d1 : d2;
      float bb = (x2lo == 1) ? e1 : e2;
      float cc = (x2lo == 1) ? d2 : d3;
      slaev2f(aa, bb, cc, &rt1, &rt2, &rc, &rs);
      // rotate cols (x2lo+1, x2lo): hi' = rc*hi - rs*lo; lo' = rs*hi + rc*lo
      {
        float lo = (x2lo == 1) ? z11 : z12;
        float hi = (x2lo == 1) ? z12 : z13;
        float nh = rc * hi - rs * lo;
        float nl = rs * hi + rc * lo;
        if (x2lo == 1) { z12 = nh; z11 = nl; } else { z13 = nh; z12 = nl; }
      }
      {
        float lo = (x2lo == 1) ? z21 : z22;
        float hi = (x2lo == 1) ? z22 : z23;
        float nh = rc * hi - rs * lo;
        float nl = rs * hi + rc * lo;
        if (x2lo == 1) { z22 = nh; z21 = nl; } else { z23 = nh; z22 = nl; }
      }
      {
        float lo = (x2lo == 1) ? z31 : z32;
        float hi = (x2lo == 1) ? z32 : z33;
        float nh = rc * hi - rs * lo;
        float nl = rs * hi + rc * lo;
        if (x2lo == 1) { z32 = nh; z31 = nl; } else { z33 = nh; z32 = nl; }
      }
      if (x2lo == 1) { d1 = rt1; d2 = rt2; e1 = 0.0f; }
      else           { d2 = rt1; d3 = rt2; e2 = 0.0f; }
      st = nst;
    }

    // ---------------- SWP: mirrored implicit-shift sweep ----------------
    if (st == ST_SWP) {
      jtot++;
      float a1 = dirQL ? d1 : d3;
      float a2 = d2;
      float a3 = dirQL ? d3 : d1;
      float b1 = dirQL ? e1 : e2;
      float b2 = dirQL ? e2 : e1;
      float g, r, rc, rs, f, b;
      g = (a2 - p) / (2.0f * b1);
      r = lapy2f(g, 1.0f);
      g = a3 - p + (b1 / (g + copysignf(r, g)));
      rs = 1.0f; rc = 1.0f; p = 0.0f;
      // step A (QL i=2 / QR i=1)
      f = rs * b2;
      b = rc * b2;
      slartgf(g, f, &rc, &rs, &r);
      g = a3 - p;
      r = (a2 - g) * rs + 2.0f * rc * b;
      p = rs * r;
      a3 = g + p;
      g = rc * r - b;
      float wcA = rc, rsA = rs;
      // step B (QL i=1 / QR i=2)
      f = rs * b1;
      b = rc * b1;
      slartgf(g, f, &rc, &rs, &r);
      b2 = r;
      g = a2 - p;
      r = (a1 - g) * rs + 2.0f * rc * b;
      p = rs * r;
      a2 = g + p;
      g = rc * r - b;
      float wcB = rc, rsB = rs;
      // rotation A on pair (hi = col(dir?3:1), lo = col2)
      if (wcA != 1.0f || rsA != 0.0f) {
        {
          float hi = dirQL ? z13 : z11, lo = z12;
          float nh = wcA * hi + rsA * lo;
          float nl = wcA * lo - rsA * hi;
          if (dirQL) z13 = nh; else z11 = nh;
          z12 = nl;
        }
        {
          float hi = dirQL ? z23 : z21, lo = z22;
          float nh = wcA * hi + rsA * lo;
          float nl = wcA * lo - rsA * hi;
          if (dirQL) z23 = nh; else z21 = nh;
          z22 = nl;
        }
        {
          float hi = dirQL ? z33 : z31, lo = z32;
          float nh = wcA * hi + rsA * lo;
          float nl = wcA * lo - rsA * hi;
          if (dirQL) z33 = nh; else z31 = nh;
          z32 = nl;
        }
      }
      // rotation B on pair (hi = col2, lo = col(dir?1:3))
      if (wcB != 1.0f || rsB != 0.0f) {
        {
          float hi = z12, lo = dirQL ? z11 : z13;
          float nh = wcB * hi + rsB * lo;
          float nl = wcB * lo - rsB * hi;
          z12 = nh;
          if (dirQL) z11 = nl; else z13 = nl;
        }
        {
          float hi = z22, lo = dirQL ? z21 : z23;
          float nh = wcB * hi + rsB * lo;
          float nl = wcB * lo - rsB * hi;
          z22 = nh;
          if (dirQL) z21 = nl; else z23 = nl;
        }
        {
          float hi = z32, lo = dirQL ? z31 : z33;
          float nh = wcB * hi + rsB * lo;
          float nl = wcB * lo - rsB * hi;
          z32 = nh;
          if (dirQL) z31 = nl; else z33 = nl;
        }
      }
      a1 = a1 - p;
      b1 = g;
      // route back
      if (dirQL) { d1 = a1; d3 = a3; e1 = b1; e2 = b2; }
      else       { d3 = a1; d1 = a3; e2 = b1; e1 = b2; }
      d2 = a2;
      st = ST_CHK;
    }

    // ---------------- RESC: L140 rescale (rare bodies) ----------------
    if (st == ST_RESC) {
      if (iscale == 1) {
        float sc = anorm / ssfmax;
        for (int q = lsv; q <= lendsv; q++)     DSET(q, DGET(q) * sc);
        for (int q = lsv; q <= lendsv - 1; q++) ESET(q, EGET(q) * sc);
      } else if (iscale == 2) {
        float sc = anorm / ssfmin;
        for (int q = lsv; q <= lendsv; q++)     DSET(q, DGET(q) * sc);
        for (int q = lsv; q <= lendsv - 1; q++) ESET(q, EGET(q) * sc);
      }
      st = (jtot < nmaxit) ? ST_SEG : ST_DONE;
    }
  }

  // ---------------- sort (L160) — lockstep, once ----------------
  {
    float p;
    for (int ii = 2; ii <= 3; ii++) {
      int i = ii - 1, kk = i;
      p = DGET(i);
      for (int j = ii; j <= 3; j++) {
        if (DGET(j) < p) { kk = j; p = DGET(j); }
      }
      if (kk != i) {
        DSET(kk, DGET(i));
        DSET(i, p);
        #pragma unroll
        for (int row = 1; row <= 3; row++) {
          float tt = ZGETC(row, i);
          ZSETC(row, i, ZGETC(row, kk));
          ZSETC(row, kk, tt);
        }
      }
    }
  }

#undef DGET
#undef DSET
#undef EGET
#undef ESET
#undef AGET
#undef ASET
#undef BGET
#undef BSET
#undef ZGETC
#undef ZSETC

  // ---- SORM2R / SLARF1F: rows 2..3 of Z, u = (0, 1, v2) ----
  if (tau1 != 0.0f) {
    {
      float z2 = z21, z3 = z31;
      float w = z2 + z3 * v2;
      float t = tau1 * w;
      z21 = __builtin_fmaf(-tau1, w, z2);
      z31 = __builtin_fmaf(v2, -t, z3);
    }
    {
      float z2 = z22, z3 = z32;
      float w = z2 + z3 * v2;
      float t = tau1 * w;
      z22 = __builtin_fmaf(-tau1, w, z2);
      z32 = __builtin_fmaf(v2, -t, z3);
    }
    {
      float z2 = z23, z3 = z33;
      float w = z2 + z3 * v2;
      float t = tau1 * w;
      z23 = __builtin_fmaf(-tau1, w, z2);
      z33 = __builtin_fmaf(v2, -t, z3);
    }
  }

  // frames = vecs^T
  o[0] = z11; o[1] = z21; o[2] = z31;
  o[3] = z12; o[4] = z22; o[5] = z32;
  o[6] = z13; o[7] = z23; o[8] = z33;
}

// ---------------------------------------------------------------------------
// Tiled single kernel: 256 threads / 64 nodes per block (measured-optimal
// L=64 geometry).  sev[node*193 + slot*3 + c]: conflict-free both phases.
// ---------------------------------------------------------------------------
#define NODES_PER_BLOCK 64
#define NODE_STRIDE     193   /* 64*3 + 1 pad */

struct __attribute__((aligned(4))) f3 { float x, y, z; };

__global__ void __launch_bounds__(256)
pca_frames_tiled_kernel(const float* __restrict__ pos,
                        const int*   __restrict__ esrc,
                        const int*   __restrict__ nn,
                        float*       __restrict__ out,
                        int n)
{
#pragma clang fp contract(off)
  __shared__ float sev[NODES_PER_BLOCK * NODE_STRIDE];          // 49408 B

  const int tid   = threadIdx.x;
  const int node0 = blockIdx.x * NODES_PER_BLOCK;

  // ---- Stage 1: cooperative gather of this block's 64*64 edges ----
  const int ebase = blockIdx.x * (NODES_PER_BLOCK * 64);
  #pragma unroll
  for (int q = 0; q < (NODES_PER_BLOCK * 64) / 256; ++q) {
    int eb  = q * 256 + tid;
    int n_b = eb >> 6;          // wave-uniform
    int j   = eb & 63;
    int i   = node0 + n_b;
    int s   = esrc[ebase + eb];
    f3 ps   = *reinterpret_cast<const f3*>(pos + 3 * s);   // packed 12B gather
    float dx = ps.x - pos[3 * i + 0];
    float dy = ps.y - pos[3 * i + 1];
    float dz = ps.z - pos[3 * i + 2];
    float* row = sev + n_b * NODE_STRIDE + 3 * j;
    row[0] = dx;
    row[1] = dy;
    row[2] = dz;
  }

  __syncthreads();

  // ---- Stage 2: wave 0, 64 lanes, one node per lane ----
  if (tid < 64) {
    int i = node0 + tid;
    float* o = out + (size_t)i * 9;

    if (nn[i] <= 1) {
      #pragma unroll
      for (int j = 0; j < 9; ++j) o[j] = 0.0f;
      return;
    }

    const float* row = sev + tid * NODE_STRIDE;
    float c00 = 0.0f, c01 = 0.0f, c02 = 0.0f, c11 = 0.0f, c12 = 0.0f, c22 = 0.0f;
    // EXACT sequential edge order, EXACT rounding (validated).
    for (int j = 0; j < 64; ++j) {
      float dx = row[3 * j + 0];
      float dy = row[3 * j + 1];
      float dz = row[3 * j + 2];
      c00 = c00 + dx * dx;
      c01 = c01 + dx * dy;
      c02 = c02 + dx * dz;
      c11 = c11 + dy * dy;
      c12 = c12 + dy * dz;
      c22 = c22 + dz * dz;
    }

    eig_frames_sm(c00, c01, c02, c11, c12, c22, o);
  }
}

// ---------------------------------------------------------------------------
// Fallback (unexpected shapes): validated fused structure, same solver.
// ---------------------------------------------------------------------------
__global__ void __launch_bounds__(64)
pca_frames_fused_kernel(const float* __restrict__ pos,
                        const int*   __restrict__ esrc,
                        const int*   __restrict__ nn,
                        float*       __restrict__ out,
                        int n, int k)
{
#pragma clang fp contract(off)
  int i = blockIdx.x * blockDim.x + threadIdx.x;
  if (i >= n) return;
  float* o = out + (size_t)i * 9;

  if (nn[i] <= 1) {
    #pragma unroll
    for (int j = 0; j < 9; ++j) o[j] = 0.0f;
    return;
  }

  float px = pos[3 * i + 0], py = pos[3 * i + 1], pz = pos[3 * i + 2];
  float c00 = 0.0f, c01 = 0.0f, c02 = 0.0f, c11 = 0.0f, c12 = 0.0f, c22 = 0.0f;
  const int* ep = esrc + (size_t)i * k;
  for (int j = 0; j < k; ++j) {
    int sidx = ep[j];
    float dx = pos[3 * sidx + 0] - px;
    float dy = pos[3 * sidx + 1] - py;
    float dz = pos[3 * sidx + 2] - pz;
    c00 = c00 + dx * dx;
    c01 = c01 + dx * dy;
    c02 = c02 + dx * dz;
    c11 = c11 + dy * dy;
    c12 = c12 + dy * dz;
    c22 = c22 + dz * dz;
  }

  eig_frames_sm(c00, c01, c02, c11, c12, c22, o);
}

extern "C" void kernel_launch(void* const* d_in, const int* in_sizes, int n_in,
                              void* d_out, int out_size, void* d_ws, size_t ws_size,
                              hipStream_t stream) {
  const float* pos  = (const float*)d_in[0];
  const int*   esrc = (const int*)d_in[1];
  // d_in[2] = edge_dst: unused (layout is repeat(arange(n), k) by construction)
  const int*   nn   = (const int*)d_in[3];
  float*       out  = (float*)d_out;

  int n = in_sizes[0] / 3;
  if (n <= 0) return;
  int k = in_sizes[1] / n;

  if (k == 64 && (n % NODES_PER_BLOCK) == 0) {
    hipLaunchKernelGGL(pca_frames_tiled_kernel, dim3(n / NODES_PER_BLOCK),
                       dim3(256), 0, stream, pos, esrc, nn, out, n);
  } else {
    const int block = 64;
    hipLaunchKernelGGL(pca_frames_fused_kernel, dim3((n + block - 1) / block),
                       dim3(block), 0, stream, pos, esrc, nn, out, n, k);
  }
}